// Round 1
// baseline (1911.174 us; speedup 1.0000x reference)
//
#include <hip/hip_runtime.h>
#include <stdint.h>

#define NNODES 50000
#define NEDGES 800000
#define NGRAPH 100

typedef _Float16 f16;
typedef __attribute__((ext_vector_type(8))) _Float16 half8;
typedef __attribute__((ext_vector_type(4))) float floatx4;

__device__ __forceinline__ void stage_WT(const float* __restrict__ W, f16* WT, int tid) {
    for (int idx = tid; idx < 128 * 128; idx += 256) {
        int k = idx >> 7, n = idx & 127;
        WT[n * 136 + k] = (f16)W[idx];
    }
}

__device__ __forceinline__ float fast_tanh(float x) {
    x = fminf(fmaxf(x, -15.0f), 15.0f);
    float e2 = __expf(2.0f * x);
    return (e2 - 1.0f) * __builtin_amdgcn_rcpf(e2 + 1.0f);
}

__global__ void init_k(float* out, int osz, int* cnt) {
    int i = blockIdx.x * 256 + threadIdx.x;
    if (i < osz) out[i] = 0.0f;
    if (i < NNODES) cnt[i] = 0;
}

__global__ void hist_k(const int* __restrict__ dst, int* __restrict__ cnt) {
    int e = blockIdx.x * 256 + threadIdx.x;
    if (e < NEDGES) atomicAdd(&cnt[dst[e]], 1);
}

__global__ __launch_bounds__(1024) void scan_k(int* __restrict__ cnt, int* __restrict__ rowStart) {
    __shared__ int buf[1024];
    __shared__ int runningS;
    int tid = threadIdx.x;
    if (tid == 0) runningS = 0;
    __syncthreads();
    for (int base = 0; base < NNODES; base += 1024) {
        int i = base + tid;
        int v = (i < NNODES) ? cnt[i] : 0;
        buf[tid] = v;
        __syncthreads();
        for (int off = 1; off < 1024; off <<= 1) {
            int t = (tid >= off) ? buf[tid - off] : 0;
            __syncthreads();
            buf[tid] += t;
            __syncthreads();
        }
        int run = runningS;
        if (i < NNODES) { rowStart[i] = run + buf[tid] - v; cnt[i] = 0; }
        __syncthreads();
        if (tid == 1023) runningS = run + buf[1023];
        __syncthreads();
    }
    if (tid == 0) rowStart[NNODES] = NEDGES;
}

__global__ void scatter_k(const int* __restrict__ src, const int* __restrict__ et,
                          const int* __restrict__ dst, const float* __restrict__ dist,
                          const int* __restrict__ rowStart, int* __restrict__ cnt,
                          int* __restrict__ srcR, int* __restrict__ etR,
                          int* __restrict__ dstR, float* __restrict__ distR) {
    int e = blockIdx.x * 256 + threadIdx.x;
    if (e >= NEDGES) return;
    int d = dst[e];
    int pos = rowStart[d] + atomicAdd(&cnt[d], 1);
    srcR[pos] = src[e];
    etR[pos] = et[e];
    dstR[pos] = d;
    distR[pos] = dist[e];
}

__global__ void gather_h(const int* __restrict__ nt, const float* __restrict__ emb,
                         float* __restrict__ h) {
    int i = blockIdx.x * 256 + threadIdx.x;
    int row = i >> 5, c4 = (i & 31) * 4;
    if (row < NNODES)
        *(floatx4*)(h + row * 128 + c4) = *(const floatx4*)(emb + nt[row] * 128 + c4);
}

template <int MODE>
__global__ __launch_bounds__(256, 1) void mlp_kernel(
        const float* __restrict__ X, int M,
        const float* __restrict__ W1, const float* __restrict__ b1,
        const float* __restrict__ W2, const float* __restrict__ b2,
        f16* __restrict__ Out) {
    __shared__ f16 W1T[128 * 136];
    __shared__ f16 W2T[(MODE == 0) ? 128 * 136 : 8];
    __shared__ f16 xBuf[64 * 136];
    __shared__ float bias1[128];
    __shared__ float bias2[128];
    int tid = threadIdx.x;

    stage_WT(W1, W1T, tid);
    if (MODE == 0) stage_WT(W2, W2T, tid);
    if (tid < 128) { bias1[tid] = b1[tid]; bias2[tid] = (MODE == 0) ? b2[tid] : 0.0f; }

    int r0 = blockIdx.x * 64;
    for (int it = 0; it < 8; ++it) {
        int row = it * 8 + (tid >> 5);
        int c4 = (tid & 31) * 4;
        int gr = r0 + row;
        floatx4 x = {0.0f, 0.0f, 0.0f, 0.0f};
        if (gr < M) x = *(const floatx4*)(X + gr * 128 + c4);
        f16* dph = xBuf + row * 136 + c4;
        dph[0] = (f16)x[0]; dph[1] = (f16)x[1]; dph[2] = (f16)x[2]; dph[3] = (f16)x[3];
    }
    __syncthreads();

    int lane = tid & 63, wv = tid >> 6;
    int R = wv * 16;
    int n16 = lane & 15, q = lane >> 4;

    half8 a[4];
    for (int kk = 0; kk < 4; ++kk)
        a[kk] = *(const half8*)(xBuf + (R + n16) * 136 + kk * 32 + q * 8);

    floatx4 acc[8];
    for (int f = 0; f < 8; ++f) {
        float bb = bias1[f * 16 + n16];
        acc[f] = (floatx4){bb, bb, bb, bb};
        for (int kk = 0; kk < 4; ++kk) {
            half8 b = *(const half8*)(W1T + (f * 16 + n16) * 136 + kk * 32 + q * 8);
            acc[f] = __builtin_amdgcn_mfma_f32_16x16x32_f16(a[kk], b, acc[f], 0, 0, 0);
        }
    }

    if (MODE == 0) {
        for (int f = 0; f < 8; ++f)
            for (int i = 0; i < 4; ++i)
                xBuf[(R + q * 4 + i) * 136 + f * 16 + n16] = (f16)fmaxf(acc[f][i], 0.0f);
        for (int kk = 0; kk < 4; ++kk)
            a[kk] = *(const half8*)(xBuf + (R + n16) * 136 + kk * 32 + q * 8);
        for (int f = 0; f < 8; ++f) {
            float bb = bias2[f * 16 + n16];
            acc[f] = (floatx4){bb, bb, bb, bb};
            for (int kk = 0; kk < 4; ++kk) {
                half8 b = *(const half8*)(W2T + (f * 16 + n16) * 136 + kk * 32 + q * 8);
                acc[f] = __builtin_amdgcn_mfma_f32_16x16x32_f16(a[kk], b, acc[f], 0, 0, 0);
            }
        }
        for (int f = 0; f < 8; ++f)
            for (int i = 0; i < 4; ++i) {
                int gr = r0 + R + q * 4 + i;
                if (gr < M) Out[gr * 128 + f * 16 + n16] = (f16)acc[f][i];
            }
    } else {
        for (int f = 0; f < 8; ++f)
            for (int i = 0; i < 4; ++i) {
                int gr = r0 + R + q * 4 + i;
                float v = acc[f][i];
                if (MODE == 1) v = fmaxf(v, 0.0f);
                if (gr < M) Out[gr * 128 + f * 16 + n16] = (f16)v;
            }
    }
}

__global__ __launch_bounds__(256, 1) void edge_kernel(
        const int* __restrict__ srcR, const int* __restrict__ etR,
        const float* __restrict__ distR, const int* __restrict__ dstR,
        const f16* __restrict__ P, const f16* __restrict__ T,
        const float* __restrict__ We1,
        const float* __restrict__ We2, const float* __restrict__ be2,
        const float* __restrict__ Wc,  const float* __restrict__ bc,
        float* __restrict__ h) {
    __shared__ f16 W2T[128 * 136];
    __shared__ f16 WcT[128 * 136];
    __shared__ f16 W1rT[128 * 40];
    __shared__ f16 uBuf[64 * 136];
    __shared__ f16 rbfA[64 * 40];
    __shared__ union UU { f16 halves[2 * 64 * 136]; float m[64 * 129]; } U;
    __shared__ float sbe2[128], sbc[128];
    __shared__ int dstSeg[64];

    f16* npB = U.halves;
    f16* prB = U.halves + 64 * 136;

    int tid = threadIdx.x;
    stage_WT(We2, W2T, tid);
    stage_WT(Wc, WcT, tid);
    for (int idx = tid; idx < 128 * 32; idx += 256) {
        int n = idx >> 5, kr = idx & 31;
        W1rT[n * 40 + kr] = (kr < 30) ? (f16)We1[(128 + kr) * 128 + n] : (f16)0.0f;
    }
    if (tid < 128) { sbe2[tid] = be2[tid]; sbc[tid] = bc[tid]; }
    __syncthreads();

    int lane = tid & 63, wv = tid >> 6;
    int R = wv * 16;
    int n16 = lane & 15, q = lane >> 4;
    const float invgap = 29.0f / 10.0f;

    for (int tile = blockIdx.x; tile < NEDGES / 64; tile += gridDim.x) {
        int r0 = tile * 64;
        {
            int row = tid >> 2, sub = tid & 3;
            int e = r0 + row;
            float d = distR[e];
            int tp = etR[e];
            int sc = srcR[e];
            if (sub == 0) dstSeg[row] = dstR[e];
            for (int i = 0; i < 8; ++i) {
                int c = sub * 8 + i;
                float cen = (float)c * (10.0f / 29.0f);
                float df = d - cen;
                float v = (c < 30) ? __expf(-df * df * invgap) : 0.0f;
                rbfA[row * 40 + c] = (f16)v;
            }
            const uint4* Tp = (const uint4*)(T + tp * 128 + sub * 32);
            const uint4* Pp = (const uint4*)(P + sc * 128 + sub * 32);
            uint4* ub = (uint4*)(uBuf + row * 136 + sub * 32);
            uint4* nb = (uint4*)(npB + row * 136 + sub * 32);
            for (int m2 = 0; m2 < 4; ++m2) { ub[m2] = Tp[m2]; nb[m2] = Pp[m2]; }
        }
        __syncthreads();

        {
            half8 ar = *(const half8*)(rbfA + (R + n16) * 40 + q * 8);
            for (int f = 0; f < 8; ++f) {
                int col = f * 16 + n16;
                floatx4 c4;
                for (int i = 0; i < 4; ++i) c4[i] = (float)uBuf[(R + q * 4 + i) * 136 + col];
                half8 br = *(const half8*)(W1rT + col * 40 + q * 8);
                c4 = __builtin_amdgcn_mfma_f32_16x16x32_f16(ar, br, c4, 0, 0, 0);
                for (int i = 0; i < 4; ++i)
                    uBuf[(R + q * 4 + i) * 136 + col] = (f16)fmaxf(c4[i], 0.0f);
            }
        }

        half8 a2[4];
        for (int kk = 0; kk < 4; ++kk)
            a2[kk] = *(const half8*)(uBuf + (R + n16) * 136 + kk * 32 + q * 8);
        floatx4 ep[8];
        for (int f = 0; f < 8; ++f) {
            float bb = sbe2[f * 16 + n16];
            ep[f] = (floatx4){bb, bb, bb, bb};
            for (int kk = 0; kk < 4; ++kk) {
                half8 b = *(const half8*)(W2T + (f * 16 + n16) * 136 + kk * 32 + q * 8);
                ep[f] = __builtin_amdgcn_mfma_f32_16x16x32_f16(a2[kk], b, ep[f], 0, 0, 0);
            }
        }

        for (int f = 0; f < 8; ++f) {
            int col = f * 16 + n16;
            for (int i = 0; i < 4; ++i) {
                float np = (float)npB[(R + q * 4 + i) * 136 + col];
                prB[(R + q * 4 + i) * 136 + col] = (f16)(np * ep[f][i]);
            }
        }

        for (int kk = 0; kk < 4; ++kk)
            a2[kk] = *(const half8*)(prB + (R + n16) * 136 + kk * 32 + q * 8);
        floatx4 mm[8];
        for (int f = 0; f < 8; ++f) {
            float bb = sbc[f * 16 + n16];
            mm[f] = (floatx4){bb, bb, bb, bb};
            for (int kk = 0; kk < 4; ++kk) {
                half8 b = *(const half8*)(WcT + (f * 16 + n16) * 136 + kk * 32 + q * 8);
                mm[f] = __builtin_amdgcn_mfma_f32_16x16x32_f16(a2[kk], b, mm[f], 0, 0, 0);
            }
        }
        __syncthreads();
        for (int f = 0; f < 8; ++f)
            for (int i = 0; i < 4; ++i)
                U.m[(R + q * 4 + i) * 129 + f * 16 + n16] = fast_tanh(mm[f][i]);
        __syncthreads();

        if (tid < 128) {
            int col = tid;
            float acc = 0.0f;
            int prev = dstSeg[0];
            for (int r = 0; r < 64; ++r) {
                int dd = dstSeg[r];
                float v = U.m[r * 129 + col];
                if (dd != prev) {
                    unsafeAtomicAdd(&h[prev * 128 + col], acc);
                    acc = v; prev = dd;
                } else acc += v;
            }
            unsafeAtomicAdd(&h[prev * 128 + col], acc);
        }
        __syncthreads();
    }
}

__global__ void dot_k(const f16* __restrict__ tbuf, const float* __restrict__ Wr2,
                      const float* __restrict__ br2, const int* __restrict__ gid,
                      float* __restrict__ out) {
    int n = blockIdx.x * 256 + threadIdx.x;
    if (n >= NNODES) return;
    float acc = 0.0f;
    const half8* tp = (const half8*)(tbuf + n * 128);
    for (int m = 0; m < 16; ++m) {
        half8 v = tp[m];
        for (int j = 0; j < 8; ++j) acc += (float)v[j] * Wr2[m * 8 + j];
    }
    unsafeAtomicAdd(&out[gid[n]], acc + br2[0]);
}

extern "C" void kernel_launch(void* const* d_in, const int* in_sizes, int n_in,
                              void* d_out, int out_size, void* d_ws, size_t ws_size,
                              hipStream_t stream) {
    (void)in_sizes; (void)n_in; (void)ws_size;
    const int*   node_types = (const int*)d_in[0];
    const int*   edge_types = (const int*)d_in[1];
    const int*   src        = (const int*)d_in[2];
    const int*   dst        = (const int*)d_in[3];
    const int*   graph_ids  = (const int*)d_in[4];
    const float* distances  = (const float*)d_in[5];
    const float* node_emb   = (const float*)d_in[7];
    const float* edge_emb   = (const float*)d_in[8];
    const float* Wn1 = (const float*)d_in[9];
    const float* bn1 = (const float*)d_in[10];
    const float* Wn2 = (const float*)d_in[11];
    const float* bn2 = (const float*)d_in[12];
    const float* We1 = (const float*)d_in[13];
    const float* be1 = (const float*)d_in[14];
    const float* We2 = (const float*)d_in[15];
    const float* be2 = (const float*)d_in[16];
    const float* Wc  = (const float*)d_in[17];
    const float* bc  = (const float*)d_in[18];
    const float* Wr1 = (const float*)d_in[19];
    const float* br1 = (const float*)d_in[20];
    const float* Wr2 = (const float*)d_in[21];
    const float* br2 = (const float*)d_in[22];

    char* w = (char*)d_ws;
    auto carve = [&](size_t bytes) { char* p = w; w += (bytes + 255) & ~(size_t)255; return p; };
    float* h      = (float*)carve((size_t)NNODES * 128 * 4);
    f16*   P      = (f16*)  carve((size_t)NNODES * 128 * 2);
    f16*   T      = (f16*)  carve((size_t)500 * 128 * 2);
    int*   rowStart = (int*)carve((size_t)(NNODES + 1) * 4);
    int*   cnt    = (int*)  carve((size_t)NNODES * 4);
    int*   srcR   = (int*)  carve((size_t)NEDGES * 4);
    int*   etR    = (int*)  carve((size_t)NEDGES * 4);
    int*   dstR   = (int*)  carve((size_t)NEDGES * 4);
    float* distR  = (float*)carve((size_t)NEDGES * 4);

    float* out = (float*)d_out;

    init_k<<<(NNODES + 255) / 256, 256, 0, stream>>>(out, out_size, cnt);
    hist_k<<<NEDGES / 256, 256, 0, stream>>>(dst, cnt);
    scan_k<<<1, 1024, 0, stream>>>(cnt, rowStart);
    scatter_k<<<NEDGES / 256, 256, 0, stream>>>(src, edge_types, dst, distances,
                                                rowStart, cnt, srcR, etR, dstR, distR);
    gather_h<<<(NNODES * 32 + 255) / 256, 256, 0, stream>>>(node_types, node_emb, h);

    for (int i = 0; i < 3; ++i) {
        mlp_kernel<2><<<(500 + 63) / 64, 256, 0, stream>>>(
            edge_emb, 500, We1 + (size_t)i * 158 * 128, be1 + i * 128, nullptr, nullptr, T);
        mlp_kernel<0><<<(NNODES + 63) / 64, 256, 0, stream>>>(
            h, NNODES, Wn1 + (size_t)i * 128 * 128, bn1 + i * 128,
            Wn2 + (size_t)i * 128 * 128, bn2 + i * 128, P);
        edge_kernel<<<256, 256, 0, stream>>>(
            srcR, etR, distR, dstR, P, T,
            We1 + (size_t)i * 158 * 128,
            We2 + (size_t)i * 128 * 128, be2 + i * 128,
            Wc + (size_t)i * 128 * 128, bc + i * 128, h);
    }

    mlp_kernel<1><<<(NNODES + 63) / 64, 256, 0, stream>>>(
        h, NNODES, Wr1, br1, nullptr, nullptr, P);
    dot_k<<<(NNODES + 255) / 256, 256, 0, stream>>>(P, Wr2, br2, graph_ids, out);
}

// Round 2
// 1029.219 us; speedup vs baseline: 1.8569x; 1.8569x over previous
//
#include <hip/hip_runtime.h>
#include <stdint.h>

#define NNODES 50000
#define NEDGES 800000
#define NGRAPH 100

typedef _Float16 f16;
typedef __attribute__((ext_vector_type(8))) _Float16 half8;
typedef __attribute__((ext_vector_type(4))) float floatx4;

// stage 128x128 fp32 row-major W[k][n] -> LDS WT[n][136 pad] fp16, float4 loads
__device__ __forceinline__ void stage_WT(const float* __restrict__ W, f16* WT,
                                         int tid, int nthr) {
    for (int idx = tid; idx < 128 * 32; idx += nthr) {
        int k = idx >> 5, n4 = (idx & 31) * 4;
        floatx4 v = *(const floatx4*)(W + k * 128 + n4);
        WT[(n4 + 0) * 136 + k] = (f16)v[0];
        WT[(n4 + 1) * 136 + k] = (f16)v[1];
        WT[(n4 + 2) * 136 + k] = (f16)v[2];
        WT[(n4 + 3) * 136 + k] = (f16)v[3];
    }
}

__device__ __forceinline__ float fast_tanh(float x) {
    x = fminf(fmaxf(x, -15.0f), 15.0f);
    float e2 = __expf(2.0f * x);
    return (e2 - 1.0f) * __builtin_amdgcn_rcpf(e2 + 1.0f);
}

__global__ void init_k(float* out, int osz, int* cnt) {
    int i = blockIdx.x * 256 + threadIdx.x;
    if (i < osz) out[i] = 0.0f;
    if (i < NNODES) cnt[i] = 0;
}

__global__ void hist_k(const int* __restrict__ dst, int* __restrict__ cnt) {
    int e = blockIdx.x * 256 + threadIdx.x;
    if (e < NEDGES) atomicAdd(&cnt[dst[e]], 1);
}

// ---- 3-kernel scan over cnt[NNODES] -> exclusive rowStart ----
__global__ __launch_bounds__(1024) void scan1_k(const int* __restrict__ cnt,
                                                int* __restrict__ rowStart,
                                                int* __restrict__ blockSum) {
    __shared__ int buf[1024];
    int tid = threadIdx.x;
    int i = blockIdx.x * 1024 + tid;
    int v = (i < NNODES) ? cnt[i] : 0;
    buf[tid] = v;
    __syncthreads();
    for (int off = 1; off < 1024; off <<= 1) {
        int t = (tid >= off) ? buf[tid - off] : 0;
        __syncthreads();
        buf[tid] += t;
        __syncthreads();
    }
    if (i < NNODES) rowStart[i] = buf[tid] - v;
    if (tid == 1023) blockSum[blockIdx.x] = buf[1023];
}

__global__ void scan2_k(int* __restrict__ blockSum, int nb) {
    if (threadIdx.x == 0) {
        int run = 0;
        for (int b = 0; b < nb; ++b) { int s = blockSum[b]; blockSum[b] = run; run += s; }
    }
}

__global__ __launch_bounds__(1024) void scan3_k(int* __restrict__ rowStart,
                                                const int* __restrict__ blockSum,
                                                int* __restrict__ cnt) {
    int i = blockIdx.x * 1024 + threadIdx.x;
    if (i < NNODES) { rowStart[i] += blockSum[blockIdx.x]; cnt[i] = 0; }
    if (i == 0) rowStart[NNODES] = NEDGES;
}

__global__ void scatter_k(const int* __restrict__ src, const int* __restrict__ et,
                          const int* __restrict__ dst, const float* __restrict__ dist,
                          const int* __restrict__ rowStart, int* __restrict__ cnt,
                          int* __restrict__ srcR, int* __restrict__ etR,
                          int* __restrict__ dstR, float* __restrict__ distR) {
    int e = blockIdx.x * 256 + threadIdx.x;
    if (e >= NEDGES) return;
    int d = dst[e];
    int pos = rowStart[d] + atomicAdd(&cnt[d], 1);
    srcR[pos] = src[e];
    etR[pos] = et[e];
    dstR[pos] = d;
    distR[pos] = dist[e];
}

__global__ void gather_h(const int* __restrict__ nt, const float* __restrict__ emb,
                         float* __restrict__ h) {
    int i = blockIdx.x * 256 + threadIdx.x;
    int row = i >> 5, c4 = (i & 31) * 4;
    if (row < NNODES)
        *(floatx4*)(h + row * 128 + c4) = *(const floatx4*)(emb + nt[row] * 128 + c4);
}

// MODE 0: relu(X@W1+b1)@W2+b2   MODE 1: relu(X@W1+b1)   MODE 2: X@W1+b1
template <int MODE>
__global__ __launch_bounds__(512, 1) void mlp_kernel(
        const float* __restrict__ X, int M,
        const float* __restrict__ W1, const float* __restrict__ b1,
        const float* __restrict__ W2, const float* __restrict__ b2,
        f16* __restrict__ Out) {
    __shared__ f16 W1T[128 * 136];
    __shared__ f16 W2T[(MODE == 0) ? 128 * 136 : 8];
    __shared__ f16 xBuf[128 * 136];
    __shared__ float bias1[128];
    __shared__ float bias2[128];
    int tid = threadIdx.x;

    stage_WT(W1, W1T, tid, 512);
    if (MODE == 0) stage_WT(W2, W2T, tid, 512);
    if (tid < 128) { bias1[tid] = b1[tid]; bias2[tid] = (MODE == 0) ? b2[tid] : 0.0f; }

    int r0 = blockIdx.x * 128;
    for (int it = 0; it < 8; ++it) {
        int row = it * 16 + (tid >> 5);
        int c4 = (tid & 31) * 4;
        int gr = r0 + row;
        floatx4 x = {0.0f, 0.0f, 0.0f, 0.0f};
        if (gr < M) x = *(const floatx4*)(X + gr * 128 + c4);
        f16* dph = xBuf + row * 136 + c4;
        dph[0] = (f16)x[0]; dph[1] = (f16)x[1]; dph[2] = (f16)x[2]; dph[3] = (f16)x[3];
    }
    __syncthreads();

    int lane = tid & 63, wv = tid >> 6;
    int R = wv * 16;
    int n16 = lane & 15, q = lane >> 4;

    half8 a[4];
    for (int kk = 0; kk < 4; ++kk)
        a[kk] = *(const half8*)(xBuf + (R + n16) * 136 + kk * 32 + q * 8);

    floatx4 acc[8];
    for (int f = 0; f < 8; ++f) {
        float bb = bias1[f * 16 + n16];
        acc[f] = (floatx4){bb, bb, bb, bb};
        for (int kk = 0; kk < 4; ++kk) {
            half8 b = *(const half8*)(W1T + (f * 16 + n16) * 136 + kk * 32 + q * 8);
            acc[f] = __builtin_amdgcn_mfma_f32_16x16x32_f16(a[kk], b, acc[f], 0, 0, 0);
        }
    }

    if (MODE == 0) {
        for (int f = 0; f < 8; ++f)
            for (int i = 0; i < 4; ++i)
                xBuf[(R + q * 4 + i) * 136 + f * 16 + n16] = (f16)fmaxf(acc[f][i], 0.0f);
        for (int kk = 0; kk < 4; ++kk)
            a[kk] = *(const half8*)(xBuf + (R + n16) * 136 + kk * 32 + q * 8);
        for (int f = 0; f < 8; ++f) {
            float bb = bias2[f * 16 + n16];
            acc[f] = (floatx4){bb, bb, bb, bb};
            for (int kk = 0; kk < 4; ++kk) {
                half8 b = *(const half8*)(W2T + (f * 16 + n16) * 136 + kk * 32 + q * 8);
                acc[f] = __builtin_amdgcn_mfma_f32_16x16x32_f16(a[kk], b, acc[f], 0, 0, 0);
            }
        }
        for (int f = 0; f < 8; ++f)
            for (int i = 0; i < 4; ++i) {
                int gr = r0 + R + q * 4 + i;
                if (gr < M) Out[gr * 128 + f * 16 + n16] = (f16)acc[f][i];
            }
    } else {
        for (int f = 0; f < 8; ++f)
            for (int i = 0; i < 4; ++i) {
                int gr = r0 + R + q * 4 + i;
                float v = acc[f][i];
                if (MODE == 1) v = fmaxf(v, 0.0f);
                if (gr < M) Out[gr * 128 + f * 16 + n16] = (f16)v;
            }
    }
}

// fused edge kernel: 512 threads (8 waves), 128 sorted edges per tile.
// u = relu(T[et] + rbf@We1rbf); ep = u@We2+be2; m = tanh((P[src]*ep)@Wc+bc);
// h[dst] += segsum(m).  Buffer reuse: prB aliases uBuf; m(f16) aliases npB.
__global__ __launch_bounds__(512, 1) void edge_kernel(
        const int* __restrict__ srcR, const int* __restrict__ etR,
        const float* __restrict__ distR, const int* __restrict__ dstR,
        const f16* __restrict__ P, const f16* __restrict__ T,
        const float* __restrict__ We1,
        const float* __restrict__ We2, const float* __restrict__ be2,
        const float* __restrict__ Wc,  const float* __restrict__ bc,
        float* __restrict__ h) {
    __shared__ f16 W2T[128 * 136];     // 34816 B
    __shared__ f16 WcT[128 * 136];     // 34816 B
    __shared__ f16 W1rT[128 * 40];     // 10240 B
    __shared__ f16 uBuf[128 * 136];    // 34816 B (u, then prod)
    __shared__ f16 npB[128 * 136];     // 34816 B (P[src], then m)
    __shared__ f16 rbfA[128 * 40];     // 10240 B
    __shared__ float sbe2[128], sbc[128];
    __shared__ int dstSeg[128];
    // total 161280 B of 163840

    int tid = threadIdx.x;
    stage_WT(We2, W2T, tid, 512);
    stage_WT(Wc, WcT, tid, 512);
    for (int idx = tid; idx < 128 * 32; idx += 512) {
        int n = idx >> 5, kr = idx & 31;
        W1rT[n * 40 + kr] = (kr < 30) ? (f16)We1[(128 + kr) * 128 + n] : (f16)0.0f;
    }
    if (tid < 128) { sbe2[tid] = be2[tid]; sbc[tid] = bc[tid]; }
    __syncthreads();

    int lane = tid & 63, wv = tid >> 6;
    int R = wv * 16;                   // 8 waves x 16 rows = 128 rows
    int n16 = lane & 15, q = lane >> 4;
    const float invgap = 29.0f / 10.0f;

    for (int tile = blockIdx.x; tile < NEDGES / 128; tile += gridDim.x) {
        int r0 = tile * 128;
        // ---- phase A: stage per-edge data (4 threads per edge) ------------
        {
            int row = tid >> 2, sub = tid & 3;
            int e = r0 + row;
            float d = distR[e];
            int tp = etR[e];
            int sc = srcR[e];
            if (sub == 0) dstSeg[row] = dstR[e];
            for (int i = 0; i < 8; ++i) {
                int c = sub * 8 + i;
                float cen = (float)c * (10.0f / 29.0f);
                float df = d - cen;
                float v = (c < 30) ? __expf(-df * df * invgap) : 0.0f;
                rbfA[row * 40 + c] = (f16)v;
            }
            const uint4* Tp = (const uint4*)(T + tp * 128 + sub * 32);
            const uint4* Pp = (const uint4*)(P + sc * 128 + sub * 32);
            uint4* ub = (uint4*)(uBuf + row * 136 + sub * 32);
            uint4* nb = (uint4*)(npB + row * 136 + sub * 32);
            for (int m2 = 0; m2 < 4; ++m2) { ub[m2] = Tp[m2]; nb[m2] = Pp[m2]; }
        }
        __syncthreads();

        // ---- phase B: u = relu(T + rbf@We1rbf)  (wave-local rows) ---------
        {
            half8 ar = *(const half8*)(rbfA + (R + n16) * 40 + q * 8);
            for (int f = 0; f < 8; ++f) {
                int col = f * 16 + n16;
                floatx4 c4;
                for (int i = 0; i < 4; ++i) c4[i] = (float)uBuf[(R + q * 4 + i) * 136 + col];
                half8 br = *(const half8*)(W1rT + col * 40 + q * 8);
                c4 = __builtin_amdgcn_mfma_f32_16x16x32_f16(ar, br, c4, 0, 0, 0);
                for (int i = 0; i < 4; ++i)
                    uBuf[(R + q * 4 + i) * 136 + col] = (f16)fmaxf(c4[i], 0.0f);
            }
        }

        // ---- phase C: ep = u @ We2 + be2 ----------------------------------
        half8 a2[4];
        for (int kk = 0; kk < 4; ++kk)
            a2[kk] = *(const half8*)(uBuf + (R + n16) * 136 + kk * 32 + q * 8);
        floatx4 ep[8];
        for (int f = 0; f < 8; ++f) {
            float bb = sbe2[f * 16 + n16];
            ep[f] = (floatx4){bb, bb, bb, bb};
            for (int kk = 0; kk < 4; ++kk) {
                half8 b = *(const half8*)(W2T + (f * 16 + n16) * 136 + kk * 32 + q * 8);
                ep[f] = __builtin_amdgcn_mfma_f32_16x16x32_f16(a2[kk], b, ep[f], 0, 0, 0);
            }
        }

        // ---- phase D: prod = P[src] * ep  (into uBuf, wave-local) ---------
        for (int f = 0; f < 8; ++f) {
            int col = f * 16 + n16;
            for (int i = 0; i < 4; ++i) {
                float np = (float)npB[(R + q * 4 + i) * 136 + col];
                uBuf[(R + q * 4 + i) * 136 + col] = (f16)(np * ep[f][i]);
            }
        }

        // ---- phase E: m = tanh(prod @ Wc + bc) ----------------------------
        for (int kk = 0; kk < 4; ++kk)
            a2[kk] = *(const half8*)(uBuf + (R + n16) * 136 + kk * 32 + q * 8);
        floatx4 mm[8];
        for (int f = 0; f < 8; ++f) {
            float bb = sbc[f * 16 + n16];
            mm[f] = (floatx4){bb, bb, bb, bb};
            for (int kk = 0; kk < 4; ++kk) {
                half8 b = *(const half8*)(WcT + (f * 16 + n16) * 136 + kk * 32 + q * 8);
                mm[f] = __builtin_amdgcn_mfma_f32_16x16x32_f16(a2[kk], b, mm[f], 0, 0, 0);
            }
        }
        // m (f16) overwrites npB — wave-local rows, no barrier needed before
        for (int f = 0; f < 8; ++f)
            for (int i = 0; i < 4; ++i)
                npB[(R + q * 4 + i) * 136 + f * 16 + n16] = (f16)fast_tanh(mm[f][i]);
        __syncthreads();   // all waves' m complete

        // ---- phase F: dst-segment reduce (4 groups x 128 cols) ------------
        {
            int g = tid >> 7, col = tid & 127;
            int rbeg = g * 32;
            float acc = 0.0f;
            int prev = dstSeg[rbeg];
            for (int r = rbeg; r < rbeg + 32; ++r) {
                int dd = dstSeg[r];
                float v = (float)npB[r * 136 + col];
                if (dd != prev) {
                    unsafeAtomicAdd(&h[prev * 128 + col], acc);
                    acc = v; prev = dd;
                } else acc += v;
            }
            unsafeAtomicAdd(&h[prev * 128 + col], acc);
        }
        __syncthreads();   // protect buffers before next tile's phase A
    }
}

__global__ void dot_k(const f16* __restrict__ tbuf, const float* __restrict__ Wr2,
                      const float* __restrict__ br2, const int* __restrict__ gid,
                      float* __restrict__ out) {
    __shared__ float sa[256];
    __shared__ int sg[256];
    int t = threadIdx.x;
    int n = blockIdx.x * 256 + t;
    float acc = 0.0f;
    int g = -1;
    if (n < NNODES) {
        const half8* tp = (const half8*)(tbuf + n * 128);
        for (int m = 0; m < 16; ++m) {
            half8 v = tp[m];
            for (int j = 0; j < 8; ++j) acc += (float)v[j] * Wr2[m * 8 + j];
        }
        acc += br2[0];
        g = gid[n];
    }
    sa[t] = acc; sg[t] = g;
    __syncthreads();
    if (n < NNODES) {
        bool head = (t == 0) || (sg[t - 1] != g);
        if (head) {
            float s = 0.0f;
            int r = t;
            while (r < 256 && sg[r] == g) { s += sa[r]; ++r; }
            unsafeAtomicAdd(&out[g], s);
        }
    }
}

extern "C" void kernel_launch(void* const* d_in, const int* in_sizes, int n_in,
                              void* d_out, int out_size, void* d_ws, size_t ws_size,
                              hipStream_t stream) {
    (void)in_sizes; (void)n_in; (void)ws_size;
    const int*   node_types = (const int*)d_in[0];
    const int*   edge_types = (const int*)d_in[1];
    const int*   src        = (const int*)d_in[2];
    const int*   dst        = (const int*)d_in[3];
    const int*   graph_ids  = (const int*)d_in[4];
    const float* distances  = (const float*)d_in[5];
    const float* node_emb   = (const float*)d_in[7];
    const float* edge_emb   = (const float*)d_in[8];
    const float* Wn1 = (const float*)d_in[9];
    const float* bn1 = (const float*)d_in[10];
    const float* Wn2 = (const float*)d_in[11];
    const float* bn2 = (const float*)d_in[12];
    const float* We1 = (const float*)d_in[13];
    const float* be1 = (const float*)d_in[14];
    const float* We2 = (const float*)d_in[15];
    const float* be2 = (const float*)d_in[16];
    const float* Wc  = (const float*)d_in[17];
    const float* bc  = (const float*)d_in[18];
    const float* Wr1 = (const float*)d_in[19];
    const float* br1 = (const float*)d_in[20];
    const float* Wr2 = (const float*)d_in[21];
    const float* br2 = (const float*)d_in[22];

    char* w = (char*)d_ws;
    auto carve = [&](size_t bytes) { char* p = w; w += (bytes + 255) & ~(size_t)255; return p; };
    float* h        = (float*)carve((size_t)NNODES * 128 * 4);
    f16*   P        = (f16*)  carve((size_t)NNODES * 128 * 2);
    f16*   T        = (f16*)  carve((size_t)500 * 128 * 2);
    int*   rowStart = (int*)  carve((size_t)(NNODES + 1) * 4);
    int*   cnt      = (int*)  carve((size_t)NNODES * 4);
    int*   blockSum = (int*)  carve((size_t)64 * 4);
    int*   srcR     = (int*)  carve((size_t)NEDGES * 4);
    int*   etR      = (int*)  carve((size_t)NEDGES * 4);
    int*   dstR     = (int*)  carve((size_t)NEDGES * 4);
    float* distR    = (float*)carve((size_t)NEDGES * 4);

    float* out = (float*)d_out;
    const int NB1 = (NNODES + 1023) / 1024;   // 49

    init_k<<<(NNODES + 255) / 256, 256, 0, stream>>>(out, out_size, cnt);
    hist_k<<<NEDGES / 256, 256, 0, stream>>>(dst, cnt);
    scan1_k<<<NB1, 1024, 0, stream>>>(cnt, rowStart, blockSum);
    scan2_k<<<1, 64, 0, stream>>>(blockSum, NB1);
    scan3_k<<<NB1, 1024, 0, stream>>>(rowStart, blockSum, cnt);
    scatter_k<<<NEDGES / 256, 256, 0, stream>>>(src, edge_types, dst, distances,
                                                rowStart, cnt, srcR, etR, dstR, distR);
    gather_h<<<(NNODES * 32 + 255) / 256, 256, 0, stream>>>(node_types, node_emb, h);

    for (int i = 0; i < 3; ++i) {
        mlp_kernel<2><<<(500 + 127) / 128, 512, 0, stream>>>(
            edge_emb, 500, We1 + (size_t)i * 158 * 128, be1 + i * 128, nullptr, nullptr, T);
        mlp_kernel<0><<<(NNODES + 127) / 128, 512, 0, stream>>>(
            h, NNODES, Wn1 + (size_t)i * 128 * 128, bn1 + i * 128,
            Wn2 + (size_t)i * 128 * 128, bn2 + i * 128, P);
        edge_kernel<<<256, 512, 0, stream>>>(
            srcR, etR, distR, dstR, P, T,
            We1 + (size_t)i * 158 * 128,
            We2 + (size_t)i * 128 * 128, be2 + i * 128,
            Wc + (size_t)i * 128 * 128, bc + i * 128, h);
    }

    mlp_kernel<1><<<(NNODES + 127) / 128, 512, 0, stream>>>(
        h, NNODES, Wr1, br1, nullptr, nullptr, P);
    dot_k<<<(NNODES + 255) / 256, 256, 0, stream>>>(P, Wr2, br2, graph_ids, out);
}

// Round 3
// 827.438 us; speedup vs baseline: 2.3097x; 1.2439x over previous
//
#include <hip/hip_runtime.h>
#include <stdint.h>

#define NNODES 50000
#define NEDGES 800000
#define NGRAPH 100
#define NTILES (NEDGES / 128)   // 6250

typedef _Float16 f16;
typedef __attribute__((ext_vector_type(8))) _Float16 half8;
typedef __attribute__((ext_vector_type(4))) float floatx4;

// stage 128x128 fp32 row-major W[k][n] -> LDS WT[n][136 pad] fp16, float4 loads
__device__ __forceinline__ void stage_WT(const float* __restrict__ W, f16* WT,
                                         int tid, int nthr) {
    for (int idx = tid; idx < 128 * 32; idx += nthr) {
        int k = idx >> 5, n4 = (idx & 31) * 4;
        floatx4 v = *(const floatx4*)(W + k * 128 + n4);
        WT[(n4 + 0) * 136 + k] = (f16)v[0];
        WT[(n4 + 1) * 136 + k] = (f16)v[1];
        WT[(n4 + 2) * 136 + k] = (f16)v[2];
        WT[(n4 + 3) * 136 + k] = (f16)v[3];
    }
}

__device__ __forceinline__ float fast_tanh(float x) {
    x = fminf(fmaxf(x, -15.0f), 15.0f);
    float e2 = __expf(2.0f * x);
    return (e2 - 1.0f) * __builtin_amdgcn_rcpf(e2 + 1.0f);
}

__global__ void init_k(float* out, int osz, int* cnt) {
    int i = blockIdx.x * 256 + threadIdx.x;
    if (i < osz) out[i] = 0.0f;
    if (i < NNODES) cnt[i] = 0;
}

__global__ void hist_k(const int* __restrict__ dst, int* __restrict__ cnt) {
    int e = blockIdx.x * 256 + threadIdx.x;
    if (e < NEDGES) atomicAdd(&cnt[dst[e]], 1);
}

__global__ __launch_bounds__(1024) void scan1_k(const int* __restrict__ cnt,
                                                int* __restrict__ rowStart,
                                                int* __restrict__ blockSum) {
    __shared__ int buf[1024];
    int tid = threadIdx.x;
    int i = blockIdx.x * 1024 + tid;
    int v = (i < NNODES) ? cnt[i] : 0;
    buf[tid] = v;
    __syncthreads();
    for (int off = 1; off < 1024; off <<= 1) {
        int t = (tid >= off) ? buf[tid - off] : 0;
        __syncthreads();
        buf[tid] += t;
        __syncthreads();
    }
    if (i < NNODES) rowStart[i] = buf[tid] - v;
    if (tid == 1023) blockSum[blockIdx.x] = buf[1023];
}

__global__ void scan2_k(int* __restrict__ blockSum, int nb) {
    if (threadIdx.x == 0) {
        int run = 0;
        for (int b = 0; b < nb; ++b) { int s = blockSum[b]; blockSum[b] = run; run += s; }
    }
}

__global__ __launch_bounds__(1024) void scan3_k(int* __restrict__ rowStart,
                                                const int* __restrict__ blockSum,
                                                int* __restrict__ cnt) {
    int i = blockIdx.x * 1024 + threadIdx.x;
    if (i < NNODES) { rowStart[i] += blockSum[blockIdx.x]; cnt[i] = 0; }
    if (i == 0) rowStart[NNODES] = NEDGES;
}

// pack (src, et, dst, dist) into one 16B record at dst-sorted position
__global__ void scatter_k(const int* __restrict__ src, const int* __restrict__ et,
                          const int* __restrict__ dst, const float* __restrict__ dist,
                          const int* __restrict__ rowStart, int* __restrict__ cnt,
                          uint4* __restrict__ packE) {
    int e = blockIdx.x * 256 + threadIdx.x;
    if (e >= NEDGES) return;
    int d = dst[e];
    int pos = rowStart[d] + atomicAdd(&cnt[d], 1);
    uint4 pk;
    pk.x = (unsigned)src[e];
    pk.y = (unsigned)et[e];
    pk.z = (unsigned)d;
    pk.w = __float_as_uint(dist[e]);
    packE[pos] = pk;
}

__global__ void gather_h(const int* __restrict__ nt, const float* __restrict__ emb,
                         float* __restrict__ h) {
    int i = blockIdx.x * 256 + threadIdx.x;
    int row = i >> 5, c4 = (i & 31) * 4;
    if (row < NNODES)
        *(floatx4*)(h + row * 128 + c4) = *(const floatx4*)(emb + nt[row] * 128 + c4);
}

// MODE 0: relu(X@W1+b1)@W2+b2   MODE 1: relu(X@W1+b1)   MODE 2: X@W1+b1
// 1024 threads, 256-row tiles, 16 waves (4/SIMD)
template <int MODE>
__global__ __launch_bounds__(1024, 4) void mlp_kernel(
        const float* __restrict__ X, int M,
        const float* __restrict__ W1, const float* __restrict__ b1,
        const float* __restrict__ W2, const float* __restrict__ b2,
        f16* __restrict__ Out) {
    __shared__ f16 W1T[128 * 136];
    __shared__ f16 W2T[(MODE == 0) ? 128 * 136 : 8];
    __shared__ f16 xBuf[256 * 136];
    __shared__ float bias1[128];
    __shared__ float bias2[128];
    int tid = threadIdx.x;

    stage_WT(W1, W1T, tid, 1024);
    if (MODE == 0) stage_WT(W2, W2T, tid, 1024);
    if (tid < 128) { bias1[tid] = b1[tid]; bias2[tid] = (MODE == 0) ? b2[tid] : 0.0f; }

    int r0 = blockIdx.x * 256;
    for (int it = 0; it < 8; ++it) {
        int row = it * 32 + (tid >> 5);
        int c4 = (tid & 31) * 4;
        int gr = r0 + row;
        floatx4 x = {0.0f, 0.0f, 0.0f, 0.0f};
        if (gr < M) x = *(const floatx4*)(X + (size_t)gr * 128 + c4);
        f16* dph = xBuf + row * 136 + c4;
        dph[0] = (f16)x[0]; dph[1] = (f16)x[1]; dph[2] = (f16)x[2]; dph[3] = (f16)x[3];
    }
    __syncthreads();

    int lane = tid & 63, wv = tid >> 6;   // 16 waves
    int R = wv * 16;
    int n16 = lane & 15, q = lane >> 4;

    half8 a[4];
    #pragma unroll
    for (int kk = 0; kk < 4; ++kk)
        a[kk] = *(const half8*)(xBuf + (R + n16) * 136 + kk * 32 + q * 8);

    floatx4 acc[8];
    #pragma unroll
    for (int f = 0; f < 8; ++f) {
        float bb = bias1[f * 16 + n16];
        acc[f] = (floatx4){bb, bb, bb, bb};
        #pragma unroll
        for (int kk = 0; kk < 4; ++kk) {
            half8 b = *(const half8*)(W1T + (f * 16 + n16) * 136 + kk * 32 + q * 8);
            acc[f] = __builtin_amdgcn_mfma_f32_16x16x32_f16(a[kk], b, acc[f], 0, 0, 0);
        }
    }

    if (MODE == 0) {
        #pragma unroll
        for (int f = 0; f < 8; ++f)
            #pragma unroll
            for (int i = 0; i < 4; ++i)
                xBuf[(R + q * 4 + i) * 136 + f * 16 + n16] = (f16)fmaxf(acc[f][i], 0.0f);
        #pragma unroll
        for (int kk = 0; kk < 4; ++kk)
            a[kk] = *(const half8*)(xBuf + (R + n16) * 136 + kk * 32 + q * 8);
        #pragma unroll
        for (int f = 0; f < 8; ++f) {
            float bb = bias2[f * 16 + n16];
            acc[f] = (floatx4){bb, bb, bb, bb};
            #pragma unroll
            for (int kk = 0; kk < 4; ++kk) {
                half8 b = *(const half8*)(W2T + (f * 16 + n16) * 136 + kk * 32 + q * 8);
                acc[f] = __builtin_amdgcn_mfma_f32_16x16x32_f16(a[kk], b, acc[f], 0, 0, 0);
            }
        }
        #pragma unroll
        for (int f = 0; f < 8; ++f)
            #pragma unroll
            for (int i = 0; i < 4; ++i) {
                int gr = r0 + R + q * 4 + i;
                if (gr < M) Out[(size_t)gr * 128 + f * 16 + n16] = (f16)acc[f][i];
            }
    } else {
        #pragma unroll
        for (int f = 0; f < 8; ++f)
            #pragma unroll
            for (int i = 0; i < 4; ++i) {
                int gr = r0 + R + q * 4 + i;
                float v = acc[f][i];
                if (MODE == 1) v = fmaxf(v, 0.0f);
                if (gr < M) Out[(size_t)gr * 128 + f * 16 + n16] = (f16)v;
            }
    }
}

// fused edge kernel: 1024 threads = 2 independent 8-wave groups; each group
// processes its own 128-edge tile. Weights shared in LDS. Per group:
//   u = relu(T[et] + rbf@We1rbf)     (rbf built in A-fragment registers)
//   ep = u@We2+be2                    (ep -> LDS in C-layout)
//   m  = tanh(((P[src] (global, A-layout) ⊙ ep)@Wc + bc)
//   h[dst] += segsum(m)
__global__ __launch_bounds__(1024, 4) void edge_kernel(
        const uint4* __restrict__ packE,
        const f16* __restrict__ P, const f16* __restrict__ T,
        const float* __restrict__ We1,
        const float* __restrict__ We2, const float* __restrict__ be2,
        const float* __restrict__ Wc,  const float* __restrict__ bc,
        float* __restrict__ h) {
    __shared__ f16 W2T[128 * 136];       // 34816 B
    __shared__ f16 WcT[128 * 136];       // 34816 B
    __shared__ f16 W1rT[128 * 40];       // 10240 B
    __shared__ f16 uBuf[2][128 * 136];   // 69632 B (T -> u -> ep -> m)
    __shared__ float sbe2[128], sbc[128];
    __shared__ int   dstSeg[2][128];
    __shared__ int   srcS[2][128];
    __shared__ float distS[2][128];
    // total ~153.6 KB of 160 KB

    int tid = threadIdx.x;
    stage_WT(We2, W2T, tid, 1024);
    stage_WT(Wc,  WcT, tid, 1024);
    for (int idx = tid; idx < 128 * 32; idx += 1024) {
        int n = idx >> 5, kr = idx & 31;
        W1rT[n * 40 + kr] = (kr < 30) ? (f16)We1[(128 + kr) * 128 + n] : (f16)0.0f;
    }
    if (tid < 128) { sbe2[tid] = be2[tid]; sbc[tid] = bc[tid]; }
    __syncthreads();

    int g = tid >> 9;                  // group 0/1
    int t = tid & 511;
    int lane = tid & 63, wvg = t >> 6; // wave within group 0..7
    int R = wvg * 16;
    int n16 = lane & 15, q = lane >> 4;
    const float invgap = 29.0f / 10.0f;
    f16* U = uBuf[g];

    int gid = blockIdx.x * 2 + g;
    int blkTiles = (NTILES - blockIdx.x * 2 + 511) / 512;  // uniform across block

    for (int it = 0; it < blkTiles; ++it) {
        int tile = gid + it * 512;
        bool active = tile < NTILES;

        // ---- phase A: stage edge records + T rows (wave-local rows) -------
        if (active) {
            int row = t >> 2, sub = t & 3;
            uint4 pk = packE[(size_t)tile * 128 + row];
            if (sub == 0) {
                dstSeg[g][row] = (int)pk.z;
                srcS[g][row]   = (int)pk.x;
                distS[g][row]  = __uint_as_float(pk.w);
            }
            const uint4* Tp = (const uint4*)(T + (size_t)pk.y * 128 + sub * 32);
            uint4* ub = (uint4*)(U + row * 136 + sub * 32);
            ub[0] = Tp[0]; ub[1] = Tp[1]; ub[2] = Tp[2]; ub[3] = Tp[3];
        }

        // ---- phase B: u = relu(T + rbf@W1r) (rbf in registers) ------------
        {
            float d = distS[g][R + n16];
            half8 ar;
            #pragma unroll
            for (int j = 0; j < 8; ++j) {
                int k = q * 8 + j;
                float c = (float)k * (10.0f / 29.0f);
                float df = d - c;
                ar[j] = (f16)((k < 30) ? __expf(-df * df * invgap) : 0.0f);
            }
            #pragma unroll
            for (int f = 0; f < 8; ++f) {
                int col = f * 16 + n16;
                floatx4 c4;
                #pragma unroll
                for (int i = 0; i < 4; ++i) c4[i] = (float)U[(R + q * 4 + i) * 136 + col];
                half8 br = *(const half8*)(W1rT + col * 40 + q * 8);
                c4 = __builtin_amdgcn_mfma_f32_16x16x32_f16(ar, br, c4, 0, 0, 0);
                #pragma unroll
                for (int i = 0; i < 4; ++i)
                    U[(R + q * 4 + i) * 136 + col] = (f16)fmaxf(c4[i], 0.0f);
            }
        }

        // ---- prefetch P[src] rows in A-layout (coalesced 16B chunks) ------
        half8 pA[4];
        {
            int srow = active ? srcS[g][R + n16] : 0;
            const f16* Pr = P + (size_t)srow * 128 + q * 8;
            #pragma unroll
            for (int kk = 0; kk < 4; ++kk) pA[kk] = *(const half8*)(Pr + kk * 32);
        }

        // ---- phase C: ep = u @ We2 + be2 ----------------------------------
        half8 a2[4];
        #pragma unroll
        for (int kk = 0; kk < 4; ++kk)
            a2[kk] = *(const half8*)(U + (R + n16) * 136 + kk * 32 + q * 8);
        floatx4 ep[8];
        #pragma unroll
        for (int f = 0; f < 8; ++f) {
            float bb = sbe2[f * 16 + n16];
            ep[f] = (floatx4){bb, bb, bb, bb};
            #pragma unroll
            for (int kk = 0; kk < 4; ++kk) {
                half8 b = *(const half8*)(W2T + (f * 16 + n16) * 136 + kk * 32 + q * 8);
                ep[f] = __builtin_amdgcn_mfma_f32_16x16x32_f16(a2[kk], b, ep[f], 0, 0, 0);
            }
        }

        // ---- phase D: ep -> LDS (C-layout, wave-local rows) ---------------
        #pragma unroll
        for (int f = 0; f < 8; ++f) {
            int col = f * 16 + n16;
            #pragma unroll
            for (int i = 0; i < 4; ++i)
                U[(R + q * 4 + i) * 136 + col] = (f16)ep[f][i];
        }

        // ---- phase E: m = tanh((P ⊙ ep) @ Wc + bc) ------------------------
        #pragma unroll
        for (int kk = 0; kk < 4; ++kk) {
            half8 pe = *(const half8*)(U + (R + n16) * 136 + kk * 32 + q * 8);
            a2[kk] = pe * pA[kk];   // v_pk_mul_f16
        }
        floatx4 mm[8];
        #pragma unroll
        for (int f = 0; f < 8; ++f) {
            float bb = sbc[f * 16 + n16];
            mm[f] = (floatx4){bb, bb, bb, bb};
            #pragma unroll
            for (int kk = 0; kk < 4; ++kk) {
                half8 b = *(const half8*)(WcT + (f * 16 + n16) * 136 + kk * 32 + q * 8);
                mm[f] = __builtin_amdgcn_mfma_f32_16x16x32_f16(a2[kk], b, mm[f], 0, 0, 0);
            }
        }
        #pragma unroll
        for (int f = 0; f < 8; ++f)
            #pragma unroll
            for (int i = 0; i < 4; ++i)
                U[(R + q * 4 + i) * 136 + f * 16 + n16] = (f16)fast_tanh(mm[f][i]);
        __syncthreads();   // all waves' m complete (block-wide)

        // ---- phase F: dst-segment reduce (4 chunks x 128 cols per group) --
        if (active) {
            int col = t & 127, chunk = t >> 7;
            int rbeg = chunk * 32;
            float acc = 0.0f;
            int prev = dstSeg[g][rbeg];
            for (int r = rbeg; r < rbeg + 32; ++r) {
                int dd = dstSeg[g][r];
                float v = (float)U[r * 136 + col];
                if (dd != prev) {
                    unsafeAtomicAdd(&h[(size_t)prev * 128 + col], acc);
                    acc = v; prev = dd;
                } else acc += v;
            }
            unsafeAtomicAdd(&h[(size_t)prev * 128 + col], acc);
        }
        __syncthreads();   // protect U before next tile's phase A
    }
}

__global__ void dot_k(const f16* __restrict__ tbuf, const float* __restrict__ Wr2,
                      const float* __restrict__ br2, const int* __restrict__ gid,
                      float* __restrict__ out) {
    __shared__ float sa[256];
    __shared__ int sg[256];
    int t = threadIdx.x;
    int n = blockIdx.x * 256 + t;
    float acc = 0.0f;
    int g = -1;
    if (n < NNODES) {
        const half8* tp = (const half8*)(tbuf + (size_t)n * 128);
        for (int m = 0; m < 16; ++m) {
            half8 v = tp[m];
            for (int j = 0; j < 8; ++j) acc += (float)v[j] * Wr2[m * 8 + j];
        }
        acc += br2[0];
        g = gid[n];
    }
    sa[t] = acc; sg[t] = g;
    __syncthreads();
    if (n < NNODES) {
        bool head = (t == 0) || (sg[t - 1] != g);
        if (head) {
            float s = 0.0f;
            int r = t;
            while (r < 256 && sg[r] == g) { s += sa[r]; ++r; }
            unsafeAtomicAdd(&out[g], s);
        }
    }
}

extern "C" void kernel_launch(void* const* d_in, const int* in_sizes, int n_in,
                              void* d_out, int out_size, void* d_ws, size_t ws_size,
                              hipStream_t stream) {
    (void)in_sizes; (void)n_in; (void)ws_size;
    const int*   node_types = (const int*)d_in[0];
    const int*   edge_types = (const int*)d_in[1];
    const int*   src        = (const int*)d_in[2];
    const int*   dst        = (const int*)d_in[3];
    const int*   graph_ids  = (const int*)d_in[4];
    const float* distances  = (const float*)d_in[5];
    const float* node_emb   = (const float*)d_in[7];
    const float* edge_emb   = (const float*)d_in[8];
    const float* Wn1 = (const float*)d_in[9];
    const float* bn1 = (const float*)d_in[10];
    const float* Wn2 = (const float*)d_in[11];
    const float* bn2 = (const float*)d_in[12];
    const float* We1 = (const float*)d_in[13];
    const float* be1 = (const float*)d_in[14];
    const float* We2 = (const float*)d_in[15];
    const float* be2 = (const float*)d_in[16];
    const float* Wc  = (const float*)d_in[17];
    const float* bc  = (const float*)d_in[18];
    const float* Wr1 = (const float*)d_in[19];
    const float* br1 = (const float*)d_in[20];
    const float* Wr2 = (const float*)d_in[21];
    const float* br2 = (const float*)d_in[22];

    char* w = (char*)d_ws;
    auto carve = [&](size_t bytes) { char* p = w; w += (bytes + 255) & ~(size_t)255; return p; };
    float* h        = (float*)carve((size_t)NNODES * 128 * 4);
    f16*   P        = (f16*)  carve((size_t)NNODES * 128 * 2);
    f16*   T        = (f16*)  carve((size_t)500 * 128 * 2);
    int*   rowStart = (int*)  carve((size_t)(NNODES + 1) * 4);
    int*   cnt      = (int*)  carve((size_t)NNODES * 4);
    int*   blockSum = (int*)  carve((size_t)64 * 4);
    uint4* packE    = (uint4*)carve((size_t)NEDGES * 16);

    float* out = (float*)d_out;
    const int NB1 = (NNODES + 1023) / 1024;   // 49

    init_k<<<(NNODES + 255) / 256, 256, 0, stream>>>(out, out_size, cnt);
    hist_k<<<NEDGES / 256, 256, 0, stream>>>(dst, cnt);
    scan1_k<<<NB1, 1024, 0, stream>>>(cnt, rowStart, blockSum);
    scan2_k<<<1, 64, 0, stream>>>(blockSum, NB1);
    scan3_k<<<NB1, 1024, 0, stream>>>(rowStart, blockSum, cnt);
    scatter_k<<<NEDGES / 256, 256, 0, stream>>>(src, edge_types, dst, distances,
                                                rowStart, cnt, packE);
    gather_h<<<(NNODES * 32 + 255) / 256, 256, 0, stream>>>(node_types, node_emb, h);

    for (int i = 0; i < 3; ++i) {
        mlp_kernel<2><<<(500 + 255) / 256, 1024, 0, stream>>>(
            edge_emb, 500, We1 + (size_t)i * 158 * 128, be1 + i * 128, nullptr, nullptr, T);
        mlp_kernel<0><<<(NNODES + 255) / 256, 1024, 0, stream>>>(
            h, NNODES, Wn1 + (size_t)i * 128 * 128, bn1 + i * 128,
            Wn2 + (size_t)i * 128 * 128, bn2 + i * 128, P);
        edge_kernel<<<256, 1024, 0, stream>>>(
            packE, P, T,
            We1 + (size_t)i * 158 * 128,
            We2 + (size_t)i * 128 * 128, be2 + i * 128,
            Wc + (size_t)i * 128 * 128, bc + i * 128, h);
    }

    mlp_kernel<1><<<(NNODES + 255) / 256, 1024, 0, stream>>>(
        h, NNODES, Wr1, br1, nullptr, nullptr, P);
    dot_k<<<(NNODES + 255) / 256, 256, 0, stream>>>(P, Wr2, br2, graph_ids, out);
}

// Round 5
// 740.162 us; speedup vs baseline: 2.5821x; 1.1179x over previous
//
#include <hip/hip_runtime.h>
#include <stdint.h>

#define NNODES 50000
#define NEDGES 800000
#define NGRAPH 100
#define NCHUNK (NEDGES / 16)   // 50000 16-edge chunks
#define NWAVES 4096            // 256 blocks x 16 waves

typedef _Float16 f16;
typedef __attribute__((ext_vector_type(8))) _Float16 half8;
typedef __attribute__((ext_vector_type(4))) _Float16 half4;
typedef __attribute__((ext_vector_type(4))) float floatx4;

// stage 128x128 fp32 row-major W[k][n] -> LDS WT[n][136 pad] fp16, float4 loads
__device__ __forceinline__ void stage_WT(const float* __restrict__ W, f16* WT,
                                         int tid, int nthr) {
    for (int idx = tid; idx < 128 * 32; idx += nthr) {
        int k = idx >> 5, n4 = (idx & 31) * 4;
        floatx4 v = *(const floatx4*)(W + k * 128 + n4);
        WT[(n4 + 0) * 136 + k] = (f16)v[0];
        WT[(n4 + 1) * 136 + k] = (f16)v[1];
        WT[(n4 + 2) * 136 + k] = (f16)v[2];
        WT[(n4 + 3) * 136 + k] = (f16)v[3];
    }
}

__device__ __forceinline__ float fast_tanh(float x) {
    x = fminf(fmaxf(x, -15.0f), 15.0f);
    float e2 = __expf(2.0f * x);
    return (e2 - 1.0f) * __builtin_amdgcn_rcpf(e2 + 1.0f);
}

// transposed-m: column c owns f16 elements [c*16, c*16+16); row groups of 4
// rotated by (c>>2) to spread banks. Bijective per column -> collision-free.
// m[r][c] lives at c*16 + ((((c>>2) + (r>>2)) & 3) << 2) + (r & 3).
__device__ __forceinline__ int mtAddr(int c, int rgroup) {
    return c * 16 + ((((c >> 2) + rgroup) & 3) << 2);
}

__global__ void init_k(float* out, int osz, int* cnt) {
    int i = blockIdx.x * 256 + threadIdx.x;
    if (i < osz) out[i] = 0.0f;
    if (i < NNODES) cnt[i] = 0;
}

__global__ void hist_k(const int* __restrict__ dst, int* __restrict__ cnt) {
    int e = blockIdx.x * 256 + threadIdx.x;
    if (e < NEDGES) atomicAdd(&cnt[dst[e]], 1);
}

__global__ __launch_bounds__(1024) void scan1_k(const int* __restrict__ cnt,
                                                int* __restrict__ rowStart,
                                                int* __restrict__ blockSum) {
    __shared__ int buf[1024];
    int tid = threadIdx.x;
    int i = blockIdx.x * 1024 + tid;
    int v = (i < NNODES) ? cnt[i] : 0;
    buf[tid] = v;
    __syncthreads();
    for (int off = 1; off < 1024; off <<= 1) {
        int t = (tid >= off) ? buf[tid - off] : 0;
        __syncthreads();
        buf[tid] += t;
        __syncthreads();
    }
    if (i < NNODES) rowStart[i] = buf[tid] - v;
    if (tid == 1023) blockSum[blockIdx.x] = buf[1023];
}

__global__ void scan2_k(int* __restrict__ blockSum, int nb) {
    if (threadIdx.x == 0) {
        int run = 0;
        for (int b = 0; b < nb; ++b) { int s = blockSum[b]; blockSum[b] = run; run += s; }
    }
}

__global__ __launch_bounds__(1024) void scan3_k(int* __restrict__ rowStart,
                                                const int* __restrict__ blockSum,
                                                int* __restrict__ cnt) {
    int i = blockIdx.x * 1024 + threadIdx.x;
    if (i < NNODES) { rowStart[i] += blockSum[blockIdx.x]; cnt[i] = 0; }
    if (i == 0) rowStart[NNODES] = NEDGES;
}

__global__ void scatter_k(const int* __restrict__ src, const int* __restrict__ et,
                          const int* __restrict__ dst, const float* __restrict__ dist,
                          const int* __restrict__ rowStart, int* __restrict__ cnt,
                          uint4* __restrict__ packE) {
    int e = blockIdx.x * 256 + threadIdx.x;
    if (e >= NEDGES) return;
    int d = dst[e];
    int pos = rowStart[d] + atomicAdd(&cnt[d], 1);
    uint4 pk;
    pk.x = (unsigned)src[e];
    pk.y = (unsigned)et[e];
    pk.z = (unsigned)d;
    pk.w = __float_as_uint(dist[e]);
    packE[pos] = pk;
}

__global__ void gather_h(const int* __restrict__ nt, const float* __restrict__ emb,
                         float* __restrict__ h) {
    int i = blockIdx.x * 256 + threadIdx.x;
    int row = i >> 5, c4 = (i & 31) * 4;
    if (row < NNODES)
        *(floatx4*)(h + row * 128 + c4) = *(const floatx4*)(emb + nt[row] * 128 + c4);
}

// MODE 0: relu(X@W1+b1)@W2+b2 -> Out f16   MODE 2: X@W1+b1 -> Out f16
template <int MODE>
__global__ __launch_bounds__(1024, 4) void mlp_kernel(
        const float* __restrict__ X, int M,
        const float* __restrict__ W1, const float* __restrict__ b1,
        const float* __restrict__ W2, const float* __restrict__ b2,
        f16* __restrict__ Out) {
    __shared__ f16 W1T[128 * 136];
    __shared__ f16 W2T[(MODE == 0) ? 128 * 136 : 8];
    __shared__ f16 xBuf[256 * 136];
    __shared__ float bias1[128];
    __shared__ float bias2[128];
    int tid = threadIdx.x;

    stage_WT(W1, W1T, tid, 1024);
    if (MODE == 0) stage_WT(W2, W2T, tid, 1024);
    if (tid < 128) { bias1[tid] = b1[tid]; bias2[tid] = (MODE == 0) ? b2[tid] : 0.0f; }

    int r0 = blockIdx.x * 256;
    for (int it = 0; it < 8; ++it) {
        int row = it * 32 + (tid >> 5);
        int c4 = (tid & 31) * 4;
        int gr = r0 + row;
        floatx4 x = {0.0f, 0.0f, 0.0f, 0.0f};
        if (gr < M) x = *(const floatx4*)(X + (size_t)gr * 128 + c4);
        f16* dph = xBuf + row * 136 + c4;
        dph[0] = (f16)x[0]; dph[1] = (f16)x[1]; dph[2] = (f16)x[2]; dph[3] = (f16)x[3];
    }
    __syncthreads();

    int lane = tid & 63, wv = tid >> 6;
    int R = wv * 16;
    int n16 = lane & 15, q = lane >> 4;

    half8 a[4];
    #pragma unroll
    for (int kk = 0; kk < 4; ++kk)
        a[kk] = *(const half8*)(xBuf + (R + n16) * 136 + kk * 32 + q * 8);

    floatx4 acc[8];
    #pragma unroll
    for (int f = 0; f < 8; ++f) {
        float bb = bias1[f * 16 + n16];
        acc[f] = (floatx4){bb, bb, bb, bb};
        #pragma unroll
        for (int kk = 0; kk < 4; ++kk) {
            half8 b = *(const half8*)(W1T + (f * 16 + n16) * 136 + kk * 32 + q * 8);
            acc[f] = __builtin_amdgcn_mfma_f32_16x16x32_f16(a[kk], b, acc[f], 0, 0, 0);
        }
    }

    if (MODE == 0) {
        #pragma unroll
        for (int f = 0; f < 8; ++f)
            #pragma unroll
            for (int i = 0; i < 4; ++i)
                xBuf[(R + q * 4 + i) * 136 + f * 16 + n16] = (f16)fmaxf(acc[f][i], 0.0f);
        #pragma unroll
        for (int kk = 0; kk < 4; ++kk)
            a[kk] = *(const half8*)(xBuf + (R + n16) * 136 + kk * 32 + q * 8);
        #pragma unroll
        for (int f = 0; f < 8; ++f) {
            float bb = bias2[f * 16 + n16];
            acc[f] = (floatx4){bb, bb, bb, bb};
            #pragma unroll
            for (int kk = 0; kk < 4; ++kk) {
                half8 b = *(const half8*)(W2T + (f * 16 + n16) * 136 + kk * 32 + q * 8);
                acc[f] = __builtin_amdgcn_mfma_f32_16x16x32_f16(a[kk], b, acc[f], 0, 0, 0);
            }
        }
        #pragma unroll
        for (int f = 0; f < 8; ++f)
            #pragma unroll
            for (int i = 0; i < 4; ++i) {
                int gr = r0 + R + q * 4 + i;
                if (gr < M) Out[(size_t)gr * 128 + f * 16 + n16] = (f16)acc[f][i];
            }
    } else {
        #pragma unroll
        for (int f = 0; f < 8; ++f)
            #pragma unroll
            for (int i = 0; i < 4; ++i) {
                int gr = r0 + R + q * 4 + i;
                if (gr < M) Out[(size_t)gr * 128 + f * 16 + n16] = (f16)acc[f][i];
            }
    }
}

// ---------------------------------------------------------------------------
// Barrier-free edge kernel. 16 waves/block, 1 block/CU. Each wave owns a
// CONTIGUOUS stripe of 16-edge chunks and runs the full pipeline wave-locally.
// No __syncthreads in the loop: all LDS deps are within one wave (in-order DS).
// ---------------------------------------------------------------------------
__global__ __launch_bounds__(1024, 4) void edge_kernel(
        const uint4* __restrict__ packE,
        const f16* __restrict__ P, const f16* __restrict__ T,
        const float* __restrict__ We1,
        const float* __restrict__ We2, const float* __restrict__ be2,
        const float* __restrict__ Wc,  const float* __restrict__ bc,
        float* __restrict__ h) {
    __shared__ f16 W2T[128 * 136];       // 34816 B
    __shared__ f16 WcT[128 * 136];       // 34816 B
    __shared__ f16 W1rT[128 * 40];       // 10240 B
    __shared__ f16 Uall[16 * 2176];      // 69632 B : per-wave 16x136 (T/u/ep) then mT
    __shared__ float sbe2[128], sbc[128];
    __shared__ int dstW[16][16];         // 1024 B
    // total ~151.5 KB -> 1 block/CU, 16 waves

    int tid = threadIdx.x;
    stage_WT(We2, W2T, tid, 1024);
    stage_WT(Wc,  WcT, tid, 1024);
    for (int idx = tid; idx < 128 * 32; idx += 1024) {
        int n = idx >> 5, kr = idx & 31;
        W1rT[n * 40 + kr] = (kr < 30) ? (f16)We1[(128 + kr) * 128 + n] : (f16)0.0f;
    }
    if (tid < 128) { sbe2[tid] = be2[tid]; sbc[tid] = bc[tid]; }
    __syncthreads();    // weights ready; the ONLY block barrier

    int lane = tid & 63, wv = tid >> 6;
    f16* U = Uall + wv * 2176;
    int* dW = dstW[wv];
    int n16 = lane & 15, q = lane >> 4;
    const float invgap = 29.0f / 10.0f;
    int colA = lane, colB = lane + 64;

    int wgid = blockIdx.x * 16 + wv;
    const int CPW = (NCHUNK + NWAVES - 1) / NWAVES;   // 13
    int c0 = wgid * CPW;
    int c1 = c0 + CPW; if (c1 > NCHUNK) c1 = NCHUNK;

    float carry0 = 0.0f, carry1 = 0.0f;
    int prev = -1;

    for (int ch = c0; ch < c1; ++ch) {
        int e0 = ch * 16;
        // ---- A: load records + distribute + stage T -----------------------
        uint4 pk = {0u, 0u, 0u, 0u};
        if (lane < 16) pk = packE[e0 + lane];
        int   ety  = __shfl((int)pk.y, lane >> 2);
        int   srcv = __shfl((int)pk.x, n16);
        float d    = __shfl(__uint_as_float(pk.w), n16);
        if (lane < 16) dW[lane] = (int)pk.z;
        {
            int row = lane >> 2, sub = lane & 3;
            const uint4* Tp = (const uint4*)(T + (size_t)ety * 128 + sub * 32);
            uint4* ub = (uint4*)(U + row * 136 + sub * 32);
            ub[0] = Tp[0]; ub[1] = Tp[1]; ub[2] = Tp[2]; ub[3] = Tp[3];
        }
        // prefetch P[src row n16] as A-frags (global, coalesced 16B)
        half8 pA[4];
        {
            const f16* Pr = P + (size_t)srcv * 128 + q * 8;
            #pragma unroll
            for (int kk = 0; kk < 4; ++kk) pA[kk] = *(const half8*)(Pr + kk * 32);
        }

        // ---- B: u = relu(T + rbf@W1r) -------------------------------------
        {
            half8 ar;
            #pragma unroll
            for (int j = 0; j < 8; ++j) {
                int k = q * 8 + j;
                float c = (float)k * (10.0f / 29.0f);
                float df = d - c;
                ar[j] = (f16)((k < 30) ? __expf(-df * df * invgap) : 0.0f);
            }
            #pragma unroll
            for (int f = 0; f < 8; ++f) {
                int col = f * 16 + n16;
                floatx4 c4;
                #pragma unroll
                for (int i = 0; i < 4; ++i) c4[i] = (float)U[(q * 4 + i) * 136 + col];
                half8 br = *(const half8*)(W1rT + col * 40 + q * 8);
                c4 = __builtin_amdgcn_mfma_f32_16x16x32_f16(ar, br, c4, 0, 0, 0);
                #pragma unroll
                for (int i = 0; i < 4; ++i)
                    U[(q * 4 + i) * 136 + col] = (f16)fmaxf(c4[i], 0.0f);
            }
        }

        // ---- C: ep = u @ We2 + be2 ----------------------------------------
        half8 a2[4];
        #pragma unroll
        for (int kk = 0; kk < 4; ++kk)
            a2[kk] = *(const half8*)(U + n16 * 136 + kk * 32 + q * 8);
        floatx4 ep[8];
        #pragma unroll
        for (int f = 0; f < 8; ++f) {
            float bb = sbe2[f * 16 + n16];
            ep[f] = (floatx4){bb, bb, bb, bb};
            #pragma unroll
            for (int kk = 0; kk < 4; ++kk) {
                half8 b = *(const half8*)(W2T + (f * 16 + n16) * 136 + kk * 32 + q * 8);
                ep[f] = __builtin_amdgcn_mfma_f32_16x16x32_f16(a2[kk], b, ep[f], 0, 0, 0);
            }
        }

        // ---- D: ep -> LDS (C-layout) --------------------------------------
        #pragma unroll
        for (int f = 0; f < 8; ++f) {
            int col = f * 16 + n16;
            #pragma unroll
            for (int i = 0; i < 4; ++i)
                U[(q * 4 + i) * 136 + col] = (f16)ep[f][i];
        }

        // ---- E: m = tanh((P ⊙ ep) @ Wc + bc); write m TRANSPOSED ----------
        #pragma unroll
        for (int kk = 0; kk < 4; ++kk) {
            half8 pe = *(const half8*)(U + n16 * 136 + kk * 32 + q * 8);
            a2[kk] = pe * pA[kk];
        }
        floatx4 mm[8];
        #pragma unroll
        for (int f = 0; f < 8; ++f) {
            float bb = sbc[f * 16 + n16];
            mm[f] = (floatx4){bb, bb, bb, bb};
            #pragma unroll
            for (int kk = 0; kk < 4; ++kk) {
                half8 b = *(const half8*)(WcT + (f * 16 + n16) * 136 + kk * 32 + q * 8);
                mm[f] = __builtin_amdgcn_mfma_f32_16x16x32_f16(a2[kk], b, mm[f], 0, 0, 0);
            }
        }
        #pragma unroll
        for (int f = 0; f < 8; ++f) {
            int c = f * 16 + n16;
            half4 mv;
            #pragma unroll
            for (int i = 0; i < 4; ++i) mv[i] = (f16)fast_tanh(mm[f][i]);
            *(half4*)(U + mtAddr(c, q)) = mv;   // rows q*4..q*4+3 of column c
        }

        // ---- F: per-col segment reduce with cross-chunk carry -------------
        {
            half4 va[4], vb[4];
            #pragma unroll
            for (int g2 = 0; g2 < 4; ++g2) {
                va[g2] = *(const half4*)(U + mtAddr(colA, g2));  // rows g2*4..+3
                vb[g2] = *(const half4*)(U + mtAddr(colB, g2));
            }
            int dArr[16];
            *(int4*)(dArr)      = *(const int4*)(dW);
            *(int4*)(dArr + 4)  = *(const int4*)(dW + 4);
            *(int4*)(dArr + 8)  = *(const int4*)(dW + 8);
            *(int4*)(dArr + 12) = *(const int4*)(dW + 12);
            #pragma unroll
            for (int r = 0; r < 16; ++r) {
                int dd = dArr[r];
                float v0 = (float)va[r >> 2][r & 3];
                float v1 = (float)vb[r >> 2][r & 3];
                if (dd != prev) {   // wave-uniform branch
                    if (prev >= 0) {
                        unsafeAtomicAdd(&h[(size_t)prev * 128 + colA], carry0);
                        unsafeAtomicAdd(&h[(size_t)prev * 128 + colB], carry1);
                    }
                    prev = dd; carry0 = v0; carry1 = v1;
                } else { carry0 += v0; carry1 += v1; }
            }
        }
    }
    if (prev >= 0) {
        unsafeAtomicAdd(&h[(size_t)prev * 128 + colA], carry0);
        unsafeAtomicAdd(&h[(size_t)prev * 128 + colB], carry1);
    }
}

// fused readout: hr = relu(h@Wr1+br1)·Wr2 + br2, out[gid] += hr  (per row)
__global__ __launch_bounds__(1024, 4) void readout_k(
        const float* __restrict__ X, int M,
        const float* __restrict__ W1, const float* __restrict__ b1,
        const float* __restrict__ Wr2, const float* __restrict__ br2,
        const int* __restrict__ gid, float* __restrict__ out) {
    __shared__ f16 W1T[128 * 136];
    __shared__ f16 xBuf[256 * 136];
    __shared__ float bias1[128];
    __shared__ float sWr2[128];
    int tid = threadIdx.x;

    stage_WT(W1, W1T, tid, 1024);
    if (tid < 128) { bias1[tid] = b1[tid]; sWr2[tid] = Wr2[tid]; }

    int r0 = blockIdx.x * 256;
    for (int it = 0; it < 8; ++it) {
        int row = it * 32 + (tid >> 5);
        int c4 = (tid & 31) * 4;
        int gr = r0 + row;
        floatx4 x = {0.0f, 0.0f, 0.0f, 0.0f};
        if (gr < M) x = *(const floatx4*)(X + (size_t)gr * 128 + c4);
        f16* dph = xBuf + row * 136 + c4;
        dph[0] = (f16)x[0]; dph[1] = (f16)x[1]; dph[2] = (f16)x[2]; dph[3] = (f16)x[3];
    }
    __syncthreads();

    int lane = tid & 63, wv = tid >> 6;
    int R = wv * 16;
    int n16 = lane & 15, q = lane >> 4;

    half8 a[4];
    #pragma unroll
    for (int kk = 0; kk < 4; ++kk)
        a[kk] = *(const half8*)(xBuf + (R + n16) * 136 + kk * 32 + q * 8);

    floatx4 acc[8];
    #pragma unroll
    for (int f = 0; f < 8; ++f) {
        float bb = bias1[f * 16 + n16];
        acc[f] = (floatx4){bb, bb, bb, bb};
        #pragma unroll
        for (int kk = 0; kk < 4; ++kk) {
            half8 b = *(const half8*)(W1T + (f * 16 + n16) * 136 + kk * 32 + q * 8);
            acc[f] = __builtin_amdgcn_mfma_f32_16x16x32_f16(a[kk], b, acc[f], 0, 0, 0);
        }
    }

    // dot with Wr2 + cross-lane reduce over n16
    float s[4];
    #pragma unroll
    for (int i = 0; i < 4; ++i) {
        float t = 0.0f;
        #pragma unroll
        for (int f = 0; f < 8; ++f)
            t += fmaxf(acc[f][i], 0.0f) * sWr2[f * 16 + n16];
        #pragma unroll
        for (int m = 1; m < 16; m <<= 1) t += __shfl_xor(t, m);
        s[i] = t;
    }

    if (n16 == 0) {
        float br2v = br2[0];
        float t = 0.0f; int g = -1;
        #pragma unroll
        for (int i = 0; i < 4; ++i) {
            int gr = r0 + R + q * 4 + i;
            if (gr < M) {
                int gi = gid[gr];
                float si = s[i] + br2v;
                if (gi == g) t += si;
                else { if (g >= 0) unsafeAtomicAdd(&out[g], t); g = gi; t = si; }
            }
        }
        if (g >= 0) unsafeAtomicAdd(&out[g], t);
    }
}

extern "C" void kernel_launch(void* const* d_in, const int* in_sizes, int n_in,
                              void* d_out, int out_size, void* d_ws, size_t ws_size,
                              hipStream_t stream) {
    (void)in_sizes; (void)n_in; (void)ws_size;
    const int*   node_types = (const int*)d_in[0];
    const int*   edge_types = (const int*)d_in[1];
    const int*   src        = (const int*)d_in[2];
    const int*   dst        = (const int*)d_in[3];
    const int*   graph_ids  = (const int*)d_in[4];
    const float* distances  = (const float*)d_in[5];
    const float* node_emb   = (const float*)d_in[7];
    const float* edge_emb   = (const float*)d_in[8];
    const float* Wn1 = (const float*)d_in[9];
    const float* bn1 = (const float*)d_in[10];
    const float* Wn2 = (const float*)d_in[11];
    const float* bn2 = (const float*)d_in[12];
    const float* We1 = (const float*)d_in[13];
    const float* be1 = (const float*)d_in[14];
    const float* We2 = (const float*)d_in[15];
    const float* be2 = (const float*)d_in[16];
    const float* Wc  = (const float*)d_in[17];
    const float* bc  = (const float*)d_in[18];
    const float* Wr1 = (const float*)d_in[19];
    const float* br1 = (const float*)d_in[20];
    const float* Wr2 = (const float*)d_in[21];
    const float* br2 = (const float*)d_in[22];

    char* w = (char*)d_ws;
    auto carve = [&](size_t bytes) { char* p = w; w += (bytes + 255) & ~(size_t)255; return p; };
    float* h        = (float*)carve((size_t)NNODES * 128 * 4);
    f16*   P        = (f16*)  carve((size_t)NNODES * 128 * 2);
    f16*   T        = (f16*)  carve((size_t)500 * 128 * 2);
    int*   rowStart = (int*)  carve((size_t)(NNODES + 1) * 4);
    int*   cnt      = (int*)  carve((size_t)NNODES * 4);
    int*   blockSum = (int*)  carve((size_t)64 * 4);
    uint4* packE    = (uint4*)carve((size_t)NEDGES * 16);

    float* out = (float*)d_out;
    const int NB1 = (NNODES + 1023) / 1024;   // 49

    init_k<<<(NNODES + 255) / 256, 256, 0, stream>>>(out, out_size, cnt);
    hist_k<<<NEDGES / 256, 256, 0, stream>>>(dst, cnt);
    scan1_k<<<NB1, 1024, 0, stream>>>(cnt, rowStart, blockSum);
    scan2_k<<<1, 64, 0, stream>>>(blockSum, NB1);
    scan3_k<<<NB1, 1024, 0, stream>>>(rowStart, blockSum, cnt);
    scatter_k<<<NEDGES / 256, 256, 0, stream>>>(src, edge_types, dst, distances,
                                                rowStart, cnt, packE);
    gather_h<<<(NNODES * 32 + 255) / 256, 256, 0, stream>>>(node_types, node_emb, h);

    for (int i = 0; i < 3; ++i) {
        mlp_kernel<2><<<(500 + 255) / 256, 1024, 0, stream>>>(
            edge_emb, 500, We1 + (size_t)i * 158 * 128, be1 + i * 128, nullptr, nullptr, T);
        mlp_kernel<0><<<(NNODES + 255) / 256, 1024, 0, stream>>>(
            h, NNODES, Wn1 + (size_t)i * 128 * 128, bn1 + i * 128,
            Wn2 + (size_t)i * 128 * 128, bn2 + i * 128, P);
        edge_kernel<<<256, 1024, 0, stream>>>(
            packE, P, T,
            We1 + (size_t)i * 158 * 128,
            We2 + (size_t)i * 128 * 128, be2 + i * 128,
            Wc + (size_t)i * 128 * 128, bc + i * 128, h);
    }

    readout_k<<<(NNODES + 255) / 256, 1024, 0, stream>>>(
        h, NNODES, Wr1, br1, Wr2, br2, graph_ids, out);
}

// Round 6
// 731.000 us; speedup vs baseline: 2.6145x; 1.0125x over previous
//
#include <hip/hip_runtime.h>
#include <stdint.h>

#define NNODES 50000
#define NEDGES 800000
#define NGRAPH 100
#define NCHUNK (NEDGES / 16)   // 50000 16-edge chunks
#define NWAVES 4096            // 256 blocks x 16 waves

typedef _Float16 f16;
typedef __attribute__((ext_vector_type(8))) _Float16 half8;
typedef __attribute__((ext_vector_type(4))) _Float16 half4;
typedef __attribute__((ext_vector_type(4))) float floatx4;

// stage 128x128 fp32 row-major W[k][n] -> LDS WT[n][136 pad] fp16, float4 loads
__device__ __forceinline__ void stage_WT(const float* __restrict__ W, f16* WT,
                                         int tid, int nthr) {
    for (int idx = tid; idx < 128 * 32; idx += nthr) {
        int k = idx >> 5, n4 = (idx & 31) * 4;
        floatx4 v = *(const floatx4*)(W + k * 128 + n4);
        WT[(n4 + 0) * 136 + k] = (f16)v[0];
        WT[(n4 + 1) * 136 + k] = (f16)v[1];
        WT[(n4 + 2) * 136 + k] = (f16)v[2];
        WT[(n4 + 3) * 136 + k] = (f16)v[3];
    }
}

__device__ __forceinline__ float fast_tanh(float x) {
    x = fminf(fmaxf(x, -15.0f), 15.0f);
    float e2 = __expf(2.0f * x);
    return (e2 - 1.0f) * __builtin_amdgcn_rcpf(e2 + 1.0f);
}

// transposed-m: column c owns f16 elements [c*16, c*16+16); row groups of 4
// rotated by (c>>2) to spread banks. Bijective per column -> collision-free.
// m[r][c] lives at c*16 + ((((c>>2) + (r>>2)) & 3) << 2) + (r & 3).
__device__ __forceinline__ int mtAddr(int c, int rgroup) {
    return c * 16 + ((((c >> 2) + rgroup) & 3) << 2);
}

__global__ void init_k(float* out, int osz, int* cnt) {
    int i = blockIdx.x * 256 + threadIdx.x;
    if (i < osz) out[i] = 0.0f;
    if (i < NNODES) cnt[i] = 0;
}

__global__ void hist_k(const int* __restrict__ dst, int* __restrict__ cnt) {
    int e = blockIdx.x * 256 + threadIdx.x;
    if (e < NEDGES) atomicAdd(&cnt[dst[e]], 1);
}

__global__ __launch_bounds__(1024) void scan1_k(const int* __restrict__ cnt,
                                                int* __restrict__ rowStart,
                                                int* __restrict__ blockSum) {
    __shared__ int buf[1024];
    int tid = threadIdx.x;
    int i = blockIdx.x * 1024 + tid;
    int v = (i < NNODES) ? cnt[i] : 0;
    buf[tid] = v;
    __syncthreads();
    for (int off = 1; off < 1024; off <<= 1) {
        int t = (tid >= off) ? buf[tid - off] : 0;
        __syncthreads();
        buf[tid] += t;
        __syncthreads();
    }
    if (i < NNODES) rowStart[i] = buf[tid] - v;
    if (tid == 1023) blockSum[blockIdx.x] = buf[1023];
}

__global__ void scan2_k(int* __restrict__ blockSum, int nb) {
    if (threadIdx.x == 0) {
        int run = 0;
        for (int b = 0; b < nb; ++b) { int s = blockSum[b]; blockSum[b] = run; run += s; }
    }
}

__global__ __launch_bounds__(1024) void scan3_k(int* __restrict__ rowStart,
                                                const int* __restrict__ blockSum,
                                                int* __restrict__ cnt) {
    int i = blockIdx.x * 1024 + threadIdx.x;
    if (i < NNODES) { rowStart[i] += blockSum[blockIdx.x]; cnt[i] = 0; }
    if (i == 0) rowStart[NNODES] = NEDGES;
}

__global__ void scatter_k(const int* __restrict__ src, const int* __restrict__ et,
                          const int* __restrict__ dst, const float* __restrict__ dist,
                          const int* __restrict__ rowStart, int* __restrict__ cnt,
                          uint4* __restrict__ packE) {
    int e = blockIdx.x * 256 + threadIdx.x;
    if (e >= NEDGES) return;
    int d = dst[e];
    int pos = rowStart[d] + atomicAdd(&cnt[d], 1);
    uint4 pk;
    pk.x = (unsigned)src[e];
    pk.y = (unsigned)et[e];
    pk.z = (unsigned)d;
    pk.w = __float_as_uint(dist[e]);
    packE[pos] = pk;
}

__global__ void gather_h(const int* __restrict__ nt, const float* __restrict__ emb,
                         float* __restrict__ h) {
    int i = blockIdx.x * 256 + threadIdx.x;
    int row = i >> 5, c4 = (i & 31) * 4;
    if (row < NNODES)
        *(floatx4*)(h + row * 128 + c4) = *(const floatx4*)(emb + nt[row] * 128 + c4);
}

// MODE 0: relu(X@W1+b1)@W2+b2 -> Out f16   MODE 2: X@W1+b1 -> Out f16
template <int MODE>
__global__ __launch_bounds__(1024, 4) void mlp_kernel(
        const float* __restrict__ X, int M,
        const float* __restrict__ W1, const float* __restrict__ b1,
        const float* __restrict__ W2, const float* __restrict__ b2,
        f16* __restrict__ Out) {
    __shared__ f16 W1T[128 * 136];
    __shared__ f16 W2T[(MODE == 0) ? 128 * 136 : 8];
    __shared__ f16 xBuf[256 * 136];
    __shared__ float bias1[128];
    __shared__ float bias2[128];
    int tid = threadIdx.x;

    stage_WT(W1, W1T, tid, 1024);
    if (MODE == 0) stage_WT(W2, W2T, tid, 1024);
    if (tid < 128) { bias1[tid] = b1[tid]; bias2[tid] = (MODE == 0) ? b2[tid] : 0.0f; }

    int r0 = blockIdx.x * 256;
    for (int it = 0; it < 8; ++it) {
        int row = it * 32 + (tid >> 5);
        int c4 = (tid & 31) * 4;
        int gr = r0 + row;
        floatx4 x = {0.0f, 0.0f, 0.0f, 0.0f};
        if (gr < M) x = *(const floatx4*)(X + (size_t)gr * 128 + c4);
        f16* dph = xBuf + row * 136 + c4;
        dph[0] = (f16)x[0]; dph[1] = (f16)x[1]; dph[2] = (f16)x[2]; dph[3] = (f16)x[3];
    }
    __syncthreads();

    int lane = tid & 63, wv = tid >> 6;
    int R = wv * 16;
    int n16 = lane & 15, q = lane >> 4;

    half8 a[4];
    #pragma unroll
    for (int kk = 0; kk < 4; ++kk)
        a[kk] = *(const half8*)(xBuf + (R + n16) * 136 + kk * 32 + q * 8);

    floatx4 acc[8];
    #pragma unroll
    for (int f = 0; f < 8; ++f) {
        float bb = bias1[f * 16 + n16];
        acc[f] = (floatx4){bb, bb, bb, bb};
        #pragma unroll
        for (int kk = 0; kk < 4; ++kk) {
            half8 b = *(const half8*)(W1T + (f * 16 + n16) * 136 + kk * 32 + q * 8);
            acc[f] = __builtin_amdgcn_mfma_f32_16x16x32_f16(a[kk], b, acc[f], 0, 0, 0);
        }
    }

    if (MODE == 0) {
        #pragma unroll
        for (int f = 0; f < 8; ++f)
            #pragma unroll
            for (int i = 0; i < 4; ++i)
                xBuf[(R + q * 4 + i) * 136 + f * 16 + n16] = (f16)fmaxf(acc[f][i], 0.0f);
        #pragma unroll
        for (int kk = 0; kk < 4; ++kk)
            a[kk] = *(const half8*)(xBuf + (R + n16) * 136 + kk * 32 + q * 8);
        #pragma unroll
        for (int f = 0; f < 8; ++f) {
            float bb = bias2[f * 16 + n16];
            acc[f] = (floatx4){bb, bb, bb, bb};
            #pragma unroll
            for (int kk = 0; kk < 4; ++kk) {
                half8 b = *(const half8*)(W2T + (f * 16 + n16) * 136 + kk * 32 + q * 8);
                acc[f] = __builtin_amdgcn_mfma_f32_16x16x32_f16(a[kk], b, acc[f], 0, 0, 0);
            }
        }
        #pragma unroll
        for (int f = 0; f < 8; ++f)
            #pragma unroll
            for (int i = 0; i < 4; ++i) {
                int gr = r0 + R + q * 4 + i;
                if (gr < M) Out[(size_t)gr * 128 + f * 16 + n16] = (f16)acc[f][i];
            }
    } else {
        #pragma unroll
        for (int f = 0; f < 8; ++f)
            #pragma unroll
            for (int i = 0; i < 4; ++i) {
                int gr = r0 + R + q * 4 + i;
                if (gr < M) Out[(size_t)gr * 128 + f * 16 + n16] = (f16)acc[f][i];
            }
    }
}

// ---------------------------------------------------------------------------
// Barrier-free edge kernel. 16 waves/block, 1 block/CU. Each wave owns a
// CONTIGUOUS stripe of 16-edge chunks and runs the full pipeline wave-locally.
// No __syncthreads in the loop: all LDS deps are within one wave (in-order DS).
// ---------------------------------------------------------------------------
__global__ __launch_bounds__(1024, 4) void edge_kernel(
        const uint4* __restrict__ packE,
        const f16* __restrict__ P, const f16* __restrict__ T,
        const float* __restrict__ We1,
        const float* __restrict__ We2, const float* __restrict__ be2,
        const float* __restrict__ Wc,  const float* __restrict__ bc,
        float* __restrict__ h) {
    __shared__ f16 W2T[128 * 136];       // 34816 B
    __shared__ f16 WcT[128 * 136];       // 34816 B
    __shared__ f16 W1rT[128 * 40];       // 10240 B
    __shared__ f16 Uall[16 * 2176];      // 69632 B : per-wave 16x136 (T/u/ep) then mT
    __shared__ float sbe2[128], sbc[128];
    __shared__ int dstW[16][16];         // 1024 B
    // total ~151.5 KB -> 1 block/CU, 16 waves

    int tid = threadIdx.x;
    stage_WT(We2, W2T, tid, 1024);
    stage_WT(Wc,  WcT, tid, 1024);
    for (int idx = tid; idx < 128 * 32; idx += 1024) {
        int n = idx >> 5, kr = idx & 31;
        W1rT[n * 40 + kr] = (kr < 30) ? (f16)We1[(128 + kr) * 128 + n] : (f16)0.0f;
    }
    if (tid < 128) { sbe2[tid] = be2[tid]; sbc[tid] = bc[tid]; }
    __syncthreads();    // weights ready; the ONLY block barrier

    int lane = tid & 63, wv = tid >> 6;
    f16* U = Uall + wv * 2176;
    int* dW = dstW[wv];
    int n16 = lane & 15, q = lane >> 4;
    const float invgap = 29.0f / 10.0f;
    int colA = lane, colB = lane + 64;

    int wgid = blockIdx.x * 16 + wv;
    const int CPW = (NCHUNK + NWAVES - 1) / NWAVES;   // 13
    int c0 = wgid * CPW;
    int c1 = c0 + CPW; if (c1 > NCHUNK) c1 = NCHUNK;

    float carry0 = 0.0f, carry1 = 0.0f;
    int prev = -1;

    for (int ch = c0; ch < c1; ++ch) {
        int e0 = ch * 16;
        // ---- A: load records + distribute + stage T -----------------------
        uint4 pk = {0u, 0u, 0u, 0u};
        if (lane < 16) pk = packE[e0 + lane];
        int   ety  = __shfl((int)pk.y, lane >> 2);
        int   srcv = __shfl((int)pk.x, n16);
        float d    = __shfl(__uint_as_float(pk.w), n16);
        if (lane < 16) dW[lane] = (int)pk.z;
        {
            int row = lane >> 2, sub = lane & 3;
            const uint4* Tp = (const uint4*)(T + (size_t)ety * 128 + sub * 32);
            uint4* ub = (uint4*)(U + row * 136 + sub * 32);
            ub[0] = Tp[0]; ub[1] = Tp[1]; ub[2] = Tp[2]; ub[3] = Tp[3];
        }
        // prefetch P[src row n16] as A-frags (global, coalesced 16B)
        half8 pA[4];
        {
            const f16* Pr = P + (size_t)srcv * 128 + q * 8;
            #pragma unroll
            for (int kk = 0; kk < 4; ++kk) pA[kk] = *(const half8*)(Pr + kk * 32);
        }

        // ---- B: u = relu(T + rbf@W1r) -------------------------------------
        {
            half8 ar;
            #pragma unroll
            for (int j = 0; j < 8; ++j) {
                int k = q * 8 + j;
                float c = (float)k * (10.0f / 29.0f);
                float df = d - c;
                ar[j] = (f16)((k < 30) ? __expf(-df * df * invgap) : 0.0f);
            }
            #pragma unroll
            for (int f = 0; f < 8; ++f) {
                int col = f * 16 + n16;
                floatx4 c4;
                #pragma unroll
                for (int i = 0; i < 4; ++i) c4[i] = (float)U[(q * 4 + i) * 136 + col];
                half8 br = *(const half8*)(W1rT + col * 40 + q * 8);
                c4 = __builtin_amdgcn_mfma_f32_16x16x32_f16(ar, br, c4, 0, 0, 0);
                #pragma unroll
                for (int i = 0; i < 4; ++i)
                    U[(q * 4 + i) * 136 + col] = (f16)fmaxf(c4[i], 0.0f);
            }
        }

        // ---- C: ep = u @ We2 + be2 ----------------------------------------
        half8 a2[4];
        #pragma unroll
        for (int kk = 0; kk < 4; ++kk)
            a2[kk] = *(const half8*)(U + n16 * 136 + kk * 32 + q * 8);
        floatx4 ep[8];
        #pragma unroll
        for (int f = 0; f < 8; ++f) {
            float bb = sbe2[f * 16 + n16];
            ep[f] = (floatx4){bb, bb, bb, bb};
            #pragma unroll
            for (int kk = 0; kk < 4; ++kk) {
                half8 b = *(const half8*)(W2T + (f * 16 + n16) * 136 + kk * 32 + q * 8);
                ep[f] = __builtin_amdgcn_mfma_f32_16x16x32_f16(a2[kk], b, ep[f], 0, 0, 0);
            }
        }

        // ---- D: ep -> LDS (C-layout) --------------------------------------
        #pragma unroll
        for (int f = 0; f < 8; ++f) {
            int col = f * 16 + n16;
            #pragma unroll
            for (int i = 0; i < 4; ++i)
                U[(q * 4 + i) * 136 + col] = (f16)ep[f][i];
        }

        // ---- E: m = tanh((P ⊙ ep) @ Wc + bc); write m TRANSPOSED ----------
        #pragma unroll
        for (int kk = 0; kk < 4; ++kk) {
            half8 pe = *(const half8*)(U + n16 * 136 + kk * 32 + q * 8);
            a2[kk] = pe * pA[kk];
        }
        floatx4 mm[8];
        #pragma unroll
        for (int f = 0; f < 8; ++f) {
            float bb = sbc[f * 16 + n16];
            mm[f] = (floatx4){bb, bb, bb, bb};
            #pragma unroll
            for (int kk = 0; kk < 4; ++kk) {
                half8 b = *(const half8*)(WcT + (f * 16 + n16) * 136 + kk * 32 + q * 8);
                mm[f] = __builtin_amdgcn_mfma_f32_16x16x32_f16(a2[kk], b, mm[f], 0, 0, 0);
            }
        }
        #pragma unroll
        for (int f = 0; f < 8; ++f) {
            int c = f * 16 + n16;
            half4 mv;
            #pragma unroll
            for (int i = 0; i < 4; ++i) mv[i] = (f16)fast_tanh(mm[f][i]);
            *(half4*)(U + mtAddr(c, q)) = mv;   // rows q*4..q*4+3 of column c
        }

        // ---- F: per-col segment reduce with cross-chunk carry -------------
        {
            half4 va[4], vb[4];
            #pragma unroll
            for (int g2 = 0; g2 < 4; ++g2) {
                va[g2] = *(const half4*)(U + mtAddr(colA, g2));  // rows g2*4..+3
                vb[g2] = *(const half4*)(U + mtAddr(colB, g2));
            }
            int dArr[16];
            *(int4*)(dArr)      = *(const int4*)(dW);
            *(int4*)(dArr + 4)  = *(const int4*)(dW + 4);
            *(int4*)(dArr + 8)  = *(const int4*)(dW + 8);
            *(int4*)(dArr + 12) = *(const int4*)(dW + 12);
            #pragma unroll
            for (int r = 0; r < 16; ++r) {
                int dd = dArr[r];
                float v0 = (float)va[r >> 2][r & 3];
                float v1 = (float)vb[r >> 2][r & 3];
                if (dd != prev) {   // wave-uniform branch
                    if (prev >= 0) {
                        unsafeAtomicAdd(&h[(size_t)prev * 128 + colA], carry0);
                        unsafeAtomicAdd(&h[(size_t)prev * 128 + colB], carry1);
                    }
                    prev = dd; carry0 = v0; carry1 = v1;
                } else { carry0 += v0; carry1 += v1; }
            }
        }
    }
    if (prev >= 0) {
        unsafeAtomicAdd(&h[(size_t)prev * 128 + colA], carry0);
        unsafeAtomicAdd(&h[(size_t)prev * 128 + colB], carry1);
    }
}

// fused readout: hr = relu(h@Wr1+br1)·Wr2 + br2, out[gid] += hr  (per row)
__global__ __launch_bounds__(1024, 4) void readout_k(
        const float* __restrict__ X, int M,
        const float* __restrict__ W1, const float* __restrict__ b1,
        const float* __restrict__ Wr2, const float* __restrict__ br2,
        const int* __restrict__ gid, float* __restrict__ out) {
    __shared__ f16 W1T[128 * 136];
    __shared__ f16 xBuf[256 * 136];
    __shared__ float bias1[128];
    __shared__ float sWr2[128];
    int tid = threadIdx.x;

    stage_WT(W1, W1T, tid, 1024);
    if (tid < 128) { bias1[tid] = b1[tid]; sWr2[tid] = Wr2[tid]; }

    int r0 = blockIdx.x * 256;
    for (int it = 0; it < 8; ++it) {
        int row = it * 32 + (tid >> 5);
        int c4 = (tid & 31) * 4;
        int gr = r0 + row;
        floatx4 x = {0.0f, 0.0f, 0.0f, 0.0f};
        if (gr < M) x = *(const floatx4*)(X + (size_t)gr * 128 + c4);
        f16* dph = xBuf + row * 136 + c4;
        dph[0] = (f16)x[0]; dph[1] = (f16)x[1]; dph[2] = (f16)x[2]; dph[3] = (f16)x[3];
    }
    __syncthreads();

    int lane = tid & 63, wv = tid >> 6;
    int R = wv * 16;
    int n16 = lane & 15, q = lane >> 4;

    half8 a[4];
    #pragma unroll
    for (int kk = 0; kk < 4; ++kk)
        a[kk] = *(const half8*)(xBuf + (R + n16) * 136 + kk * 32 + q * 8);

    floatx4 acc[8];
    #pragma unroll
    for (int f = 0; f < 8; ++f) {
        float bb = bias1[f * 16 + n16];
        acc[f] = (floatx4){bb, bb, bb, bb};
        #pragma unroll
        for (int kk = 0; kk < 4; ++kk) {
            half8 b = *(const half8*)(W1T + (f * 16 + n16) * 136 + kk * 32 + q * 8);
            acc[f] = __builtin_amdgcn_mfma_f32_16x16x32_f16(a[kk], b, acc[f], 0, 0, 0);
        }
    }

    // dot with Wr2 + cross-lane reduce over n16
    float s[4];
    #pragma unroll
    for (int i = 0; i < 4; ++i) {
        float t = 0.0f;
        #pragma unroll
        for (int f = 0; f < 8; ++f)
            t += fmaxf(acc[f][i], 0.0f) * sWr2[f * 16 + n16];
        #pragma unroll
        for (int m = 1; m < 16; m <<= 1) t += __shfl_xor(t, m);
        s[i] = t;
    }

    if (n16 == 0) {
        float br2v = br2[0];
        float t = 0.0f; int g = -1;
        #pragma unroll
        for (int i = 0; i < 4; ++i) {
            int gr = r0 + R + q * 4 + i;
            if (gr < M) {
                int gi = gid[gr];
                float si = s[i] + br2v;
                if (gi == g) t += si;
                else { if (g >= 0) unsafeAtomicAdd(&out[g], t); g = gi; t = si; }
            }
        }
        if (g >= 0) unsafeAtomicAdd(&out[g], t);
    }
}

extern "C" void kernel_launch(void* const* d_in, const int* in_sizes, int n_in,
                              void* d_out, int out_size, void* d_ws, size_t ws_size,
                              hipStream_t stream) {
    (void)in_sizes; (void)n_in; (void)ws_size;
    const int*   node_types = (const int*)d_in[0];
    const int*   edge_types = (const int*)d_in[1];
    const int*   src        = (const int*)d_in[2];
    const int*   dst        = (const int*)d_in[3];
    const int*   graph_ids  = (const int*)d_in[4];
    const float* distances  = (const float*)d_in[5];
    const float* node_emb   = (const float*)d_in[7];
    const float* edge_emb   = (const float*)d_in[8];
    const float* Wn1 = (const float*)d_in[9];
    const float* bn1 = (const float*)d_in[10];
    const float* Wn2 = (const float*)d_in[11];
    const float* bn2 = (const float*)d_in[12];
    const float* We1 = (const float*)d_in[13];
    const float* be1 = (const float*)d_in[14];
    const float* We2 = (const float*)d_in[15];
    const float* be2 = (const float*)d_in[16];
    const float* Wc  = (const float*)d_in[17];
    const float* bc  = (const float*)d_in[18];
    const float* Wr1 = (const float*)d_in[19];
    const float* br1 = (const float*)d_in[20];
    const float* Wr2 = (const float*)d_in[21];
    const float* br2 = (const float*)d_in[22];

    char* w = (char*)d_ws;
    auto carve = [&](size_t bytes) { char* p = w; w += (bytes + 255) & ~(size_t)255; return p; };
    float* h        = (float*)carve((size_t)NNODES * 128 * 4);
    f16*   P        = (f16*)  carve((size_t)NNODES * 128 * 2);
    f16*   T        = (f16*)  carve((size_t)500 * 128 * 2);
    int*   rowStart = (int*)  carve((size_t)(NNODES + 1) * 4);
    int*   cnt      = (int*)  carve((size_t)NNODES * 4);
    int*   blockSum = (int*)  carve((size_t)64 * 4);
    uint4* packE    = (uint4*)carve((size_t)NEDGES * 16);

    float* out = (float*)d_out;
    const int NB1 = (NNODES + 1023) / 1024;   // 49

    init_k<<<(NNODES + 255) / 256, 256, 0, stream>>>(out, out_size, cnt);
    hist_k<<<NEDGES / 256, 256, 0, stream>>>(dst, cnt);
    scan1_k<<<NB1, 1024, 0, stream>>>(cnt, rowStart, blockSum);
    scan2_k<<<1, 64, 0, stream>>>(blockSum, NB1);
    scan3_k<<<NB1, 1024, 0, stream>>>(rowStart, blockSum, cnt);
    scatter_k<<<NEDGES / 256, 256, 0, stream>>>(src, edge_types, dst, distances,
                                                rowStart, cnt, packE);
    gather_h<<<(NNODES * 32 + 255) / 256, 256, 0, stream>>>(node_types, node_emb, h);

    for (int i = 0; i < 3; ++i) {
        mlp_kernel<2><<<(500 + 255) / 256, 1024, 0, stream>>>(
            edge_emb, 500, We1 + (size_t)i * 158 * 128, be1 + i * 128, nullptr, nullptr, T);
        mlp_kernel<0><<<(NNODES + 255) / 256, 1024, 0, stream>>>(
            h, NNODES, Wn1 + (size_t)i * 128 * 128, bn1 + i * 128,
            Wn2 + (size_t)i * 128 * 128, bn2 + i * 128, P);
        edge_kernel<<<256, 1024, 0, stream>>>(
            packE, P, T,
            We1 + (size_t)i * 158 * 128,
            We2 + (size_t)i * 128 * 128, be2 + i * 128,
            Wc + (size_t)i * 128 * 128, bc + i * 128, h);
    }

    readout_k<<<(NNODES + 255) / 256, 1024, 0, stream>>>(
        h, NNODES, Wr1, br1, Wr2, br2, graph_ids, out);
}